// Round 12
// baseline (363.682 us; speedup 1.0000x reference)
//
#include <hip/hip_runtime.h>

#define NNODES 100000
#define NEDGES 1600000
#define BK_CAP 210000     // per-bucket capacity; E[size]=200K, sigma~418 -> +24 sigma

typedef short bhalf8 __attribute__((ext_vector_type(8)));   // 8 bf16 bit patterns
typedef float f32x4 __attribute__((ext_vector_type(4)));

__device__ __forceinline__ unsigned fbits(float x){ union{float f;unsigned u;}c; c.f=x; return c.u; }
__device__ __forceinline__ float bcast(unsigned u){ union{float f;unsigned u;}c; c.u=u; return c.f; }
// round-to-nearest-even bf16 (top 16 bits of fp32)
__device__ __forceinline__ unsigned short rtn16(float x){
    unsigned u = fbits(x);
    return (unsigned short)((u + 0x7FFFu + ((u >> 16) & 1u)) >> 16);
}
__device__ __forceinline__ float b2f(unsigned short b){ return bcast((unsigned)b << 16); }

// ---------------- edge dtype detect: int64 vs int32 ----------------
__global__ void detect_kernel(const int* __restrict__ ei, int* __restrict__ flag) {
    int t = threadIdx.x;                 // 0..63
    int v = ei[2 * t + 1];
    unsigned long long nz = __ballot(v != 0);
    if (t == 0) flag[0] = (nz == 0ULL) ? 1 : 0;   // 1 => int64 layout
}

// ---------------- bucketize: ei -> 8 dst-range buckets of (s,d) pairs ------
// LDS-count + block reservation => dense bucket runs (no write amplification).
// Degree histogram fused. 8 global reservation atomics per 2048-edge chunk.
__global__ __launch_bounds__(256) void bucketize(
    const int* __restrict__ ei, const int* __restrict__ flag,
    int2* __restrict__ pairs, int* __restrict__ bcur, int* __restrict__ deg) {
    const int is64 = flag[0];
    __shared__ int cnt[8], base[8], rnk[8];
    int t = threadIdx.x;
    for (long start = (long)blockIdx.x * 2048; start < NEDGES;
         start += (long)gridDim.x * 2048) {
        __syncthreads();                 // protect prior iter's base/rnk
        if (t < 8) cnt[t] = 0;
        __syncthreads();
        int sv[8], dv[8], bk[8];
#pragma unroll
        for (int k = 0; k < 8; ++k) {
            long e = start + k * 256 + t;
            bk[k] = -1;
            if (e < NEDGES) {
                int s = is64 ? ei[2 * e] : ei[e];
                int d = is64 ? ei[2 * (NEDGES + e)] : ei[NEDGES + e];
                sv[k] = s; dv[k] = d; bk[k] = d / 12500;
                atomicAdd(&cnt[bk[k]], 1);      // LDS
                atomicAdd(&deg[d], 1);          // global hist
            }
        }
        __syncthreads();
        if (t < 8) { base[t] = atomicAdd(&bcur[t], cnt[t]); rnk[t] = 0; }
        __syncthreads();
#pragma unroll
        for (int k = 0; k < 8; ++k) {
            if (bk[k] >= 0) {
                int r = atomicAdd(&rnk[bk[k]], 1);   // LDS rank
                pairs[(size_t)bk[k] * BK_CAP + base[bk[k]] + r] =
                    make_int2(sv[k], dv[k]);
            }
        }
    }
}

__global__ void scan_bsum(const int* __restrict__ deg, int* __restrict__ bsums) {
    int b = blockIdx.x, t = threadIdx.x;
    long i0 = (long)b * 1024 + (long)t * 4;
    int v0 = 0, v1 = 0, v2 = 0, v3 = 0;
    if (i0 + 3 < NNODES) {
        int4 q = *(const int4*)&deg[i0];
        v0 = q.x; v1 = q.y; v2 = q.z; v3 = q.w;
    } else {
        if (i0 + 0 < NNODES) v0 = deg[i0 + 0];
        if (i0 + 1 < NNODES) v1 = deg[i0 + 1];
        if (i0 + 2 < NNODES) v2 = deg[i0 + 2];
        if (i0 + 3 < NNODES) v3 = deg[i0 + 3];
    }
    int s = v0 + v1 + v2 + v3;
    for (int off = 32; off > 0; off >>= 1) s += __shfl_down(s, off);
    __shared__ int ws[4];
    if ((t & 63) == 0) ws[t >> 6] = s;
    __syncthreads();
    if (t == 0) bsums[b] = ws[0] + ws[1] + ws[2] + ws[3];
}

__global__ void scan_partials(int* __restrict__ bsums, int nb) {
    __shared__ int sm[128];
    int t = threadIdx.x;
    int v = (t < nb) ? bsums[t] : 0;
    int run = v;
    sm[t] = run;
    __syncthreads();
    for (int off = 1; off < 128; off <<= 1) {
        int other = (t >= off) ? sm[t - off] : 0;
        __syncthreads();
        run += other;
        sm[t] = run;
        __syncthreads();
    }
    if (t < nb) bsums[t] = run - v;      // exclusive
}

// pass 3: write exclusive offsets into offs AND cursor
__global__ void scan_write(const int* __restrict__ deg, const int* __restrict__ bsums,
                           int* __restrict__ offs, int* __restrict__ cursor) {
    int b = blockIdx.x, t = threadIdx.x;
    long i0 = (long)b * 1024 + (long)t * 4;
    int v0 = 0, v1 = 0, v2 = 0, v3 = 0;
    if (i0 + 3 < NNODES) {
        int4 q = *(const int4*)&deg[i0];
        v0 = q.x; v1 = q.y; v2 = q.z; v3 = q.w;
    } else {
        if (i0 + 0 < NNODES) v0 = deg[i0 + 0];
        if (i0 + 1 < NNODES) v1 = deg[i0 + 1];
        if (i0 + 2 < NNODES) v2 = deg[i0 + 2];
        if (i0 + 3 < NNODES) v3 = deg[i0 + 3];
    }
    int tot = v0 + v1 + v2 + v3;
    __shared__ int sm[256];
    int run = tot;
    sm[t] = run;
    __syncthreads();
    for (int off = 1; off < 256; off <<= 1) {
        int other = (t >= off) ? sm[t - off] : 0;
        __syncthreads();
        run += other;
        sm[t] = run;
        __syncthreads();
    }
    int excl = run - tot + bsums[b];
    int o0 = excl, o1 = excl + v0, o2 = excl + v0 + v1, o3 = excl + v0 + v1 + v2;
    if (i0 + 0 < NNODES) { offs[i0 + 0] = o0; cursor[i0 + 0] = o0; }
    if (i0 + 1 < NNODES) { offs[i0 + 1] = o1; cursor[i0 + 1] = o1; }
    if (i0 + 2 < NNODES) { offs[i0 + 2] = o2; cursor[i0 + 2] = o2; }
    if (i0 + 3 < NNODES) { offs[i0 + 3] = o3; cursor[i0 + 3] = o3; }
    if (b == 0 && t == 0) offs[NNODES] = NEDGES;
}

// fine scatter: cohort b (XCD-aligned) reads ONLY its contiguous bucket slice
// (1.6MB/XCD) -> dirty csr window (800KB) survives in L2, writes stay merged.
__global__ void scatter_fine(const int2* __restrict__ pairs, const int* __restrict__ bcur,
                             int* __restrict__ cursor, int* __restrict__ csr) {
    const int b = blockIdx.x & 7;
    const int n = bcur[b];
    const int nb = gridDim.x >> 3;
    const int2* P = pairs + (size_t)b * BK_CAP;
    for (int i = (blockIdx.x >> 3) * blockDim.x + threadIdx.x; i < n;
         i += nb * blockDim.x) {
        int2 p = P[i];
        int pos = atomicAdd(&cursor[p.y], 1);
        csr[pos] = p.x;
    }
}

// ---------------- weight prep: fp32 -> bf16 2-way split (RTN) in B-frag order
template <int K, int NL, int NTOT>
__global__ void prep_w(const float* __restrict__ wl, const float* __restrict__ wr,
                       unsigned short* __restrict__ Bh, unsigned short* __restrict__ Bl) {
    constexpr int NCT = NTOT / 16;
    constexpr int TOT = (K / 32) * NCT * 512;
    for (int idx = blockIdx.x * blockDim.x + threadIdx.x; idx < TOT;
         idx += gridDim.x * blockDim.x) {
        int e = idx & 7, l = (idx >> 3) & 63, rest = idx >> 9;
        int ct = rest % NCT, kc = rest / NCT;
        int k = kc * 32 + (l >> 4) * 8 + e;
        int j = ct * 16 + (l & 15);
        float v = (j < NL) ? wl[k * NL + j] : wr[k * NL + (j - NL)];
        unsigned short h = rtn16(v);
        float r1 = v - bcast((unsigned)h << 16);    // exact residual
        Bh[idx] = h;
        Bl[idx] = rtn16(r1);
    }
}

// ---------------- MFMA dual GEMM: Z = h @ [wl|wr], 2-way RTN split, 3 MFMA
template <int K, int NL, int NTOT>
__global__ __launch_bounds__(256) void gemm_mfma(
    const float* __restrict__ h, const unsigned short* __restrict__ Bh,
    const unsigned short* __restrict__ Bl, const float* __restrict__ bias,
    unsigned short* __restrict__ zl, float* __restrict__ zr, int nrows) {
    constexpr int NCT = NTOT / 16;
    constexpr int NKC = K / 32;
    int t = threadIdx.x;
    int l = t & 63, w = t >> 6;
    int rb = blockIdx.x * 64 + w * 16;
    int arow = rb + (l & 15);
    int kg = l >> 4;
    f32x4 acc[NCT];
#pragma unroll
    for (int ct = 0; ct < NCT; ++ct) acc[ct] = (f32x4){0.f, 0.f, 0.f, 0.f};
    const bool aok = (arow < nrows);
    const float* hrow = h + (long)arow * K + kg * 8;
#pragma unroll
    for (int kc = 0; kc < NKC; ++kc) {
        float4 a0 = make_float4(0.f, 0.f, 0.f, 0.f), a1 = a0;
        if (aok) {
            a0 = *(const float4*)(hrow + kc * 32);
            a1 = *(const float4*)(hrow + kc * 32 + 4);
        }
        float av[8] = {a0.x, a0.y, a0.z, a0.w, a1.x, a1.y, a1.z, a1.w};
        bhalf8 ah, al;
#pragma unroll
        for (int e = 0; e < 8; ++e) {
            unsigned short hh = rtn16(av[e]);
            float r1 = av[e] - bcast((unsigned)hh << 16);
            ah[e] = (short)hh;
            al[e] = (short)rtn16(r1);
        }
        const unsigned short* hp = Bh + (size_t)(kc * NCT) * 512 + l * 8;
        const unsigned short* lp = Bl + (size_t)(kc * NCT) * 512 + l * 8;
#pragma unroll
        for (int ct = 0; ct < NCT; ++ct) {
            bhalf8 bh = *(const bhalf8*)(hp + ct * 512);
            bhalf8 bl = *(const bhalf8*)(lp + ct * 512);
            acc[ct] = __builtin_amdgcn_mfma_f32_16x16x32_bf16(ah, bh, acc[ct], 0, 0, 0);
            acc[ct] = __builtin_amdgcn_mfma_f32_16x16x32_bf16(ah, bl, acc[ct], 0, 0, 0);
            acc[ct] = __builtin_amdgcn_mfma_f32_16x16x32_bf16(al, bh, acc[ct], 0, 0, 0);
        }
    }
    // D: col = l&15, row = rb + (l>>4)*4 + r   [m89-verified]
    int orow0 = rb + kg * 4;
#pragma unroll
    for (int ct = 0; ct < NCT; ++ct) {
        int j = ct * 16 + (l & 15);
        bool isl = (j < NL);
        int cc = isl ? j : j - NL;
        float bj = isl ? 0.f : bias[cc];
#pragma unroll
        for (int r = 0; r < 4; ++r) {
            int orow = orow0 + r;
            if (orow < nrows) {
                if (isl) zl[(long)orow * NL + cc] = rtn16(acc[ct][r]);
                else     zr[(long)orow * NL + cc] = acc[ct][r] + bj;
            }
        }
    }
}

// ---------------- aggregate + combine + epilogue ----------------
// bf16 zl gather (128B rows), float4-wide columns per 16-lane group, 4 edge
// slots (q); __shfl always convergent (clamped source, unconditional).
// MODE: 0=relu,1=bn+relu,2=bn
template <int NOUT, int MODE>
__global__ __launch_bounds__(256) void combine_kernel(
    const unsigned short* __restrict__ zl, const float* __restrict__ zr,
    const int* __restrict__ offs, const int* __restrict__ csr,
    const float* __restrict__ g, const float* __restrict__ bb,
    const float* __restrict__ m, const float* __restrict__ v,
    float* __restrict__ out) {
    int wid  = (blockIdx.x * blockDim.x + threadIdx.x) >> 6;
    int lane = threadIdx.x & 63;
    if (wid >= NNODES) return;          // wave-uniform
    int q   = lane >> 4;            // edge slot 0..3
    int li4 = (lane & 15) * 4;      // column group
    const bool cok = (li4 < NOUT);
    // hoisted epilogue loads (independent of the gather chain)
    float4 zrv = make_float4(0.f, 0.f, 0.f, 0.f);
    float4 gv = zrv, bv = zrv, mv = zrv, vv2 = zrv;
    if (cok) {
        zrv = *(const float4*)&zr[(long)wid * NOUT + li4];
        if (MODE == 1 || MODE == 2) {
            gv  = *(const float4*)&g[li4];
            bv  = *(const float4*)&bb[li4];
            mv  = *(const float4*)&m[li4];
            vv2 = *(const float4*)&v[li4];
        }
    }
    int s0 = offs[wid], s1 = offs[wid + 1];
    float ax = 0.f, ay = 0.f, az = 0.f, aw = 0.f;
    for (int base = s0; base < s1; base += 64) {   // uniform bounds
        int c = min(64, s1 - base);                // >= 1 here
        int cm1 = c - 1;
        int sv = (base + lane < s1) ? csr[base + lane] : 0;
        for (int p0 = 0; p0 < c; p0 += 32) {       // uniform
            ushort4 hv[8];
            bool okk[8];
#pragma unroll
            for (int j = 0; j < 8; ++j) {
                int eidx = p0 + 4 * j + q;
                okk[j] = (eidx < c);
                int srow = __shfl(sv, min(eidx, cm1));   // all lanes, convergent
                ushort4 tv = make_ushort4(0, 0, 0, 0);
                if (cok) tv = *(const ushort4*)&zl[(long)srow * NOUT + li4];
                hv[j] = tv;
            }
#pragma unroll
            for (int j = 0; j < 8; ++j) {
                if (okk[j]) {
                    ax += b2f(hv[j].x); ay += b2f(hv[j].y);
                    az += b2f(hv[j].z); aw += b2f(hv[j].w);
                }
            }
        }
    }
    // reduce across the 4 edge slots — all 64 lanes participate (convergent)
    ax += __shfl_xor(ax, 16); ay += __shfl_xor(ay, 16);
    az += __shfl_xor(az, 16); aw += __shfl_xor(aw, 16);
    ax += __shfl_xor(ax, 32); ay += __shfl_xor(ay, 32);
    az += __shfl_xor(az, 32); aw += __shfl_xor(aw, 32);
    if (q != 0 || !cok) return;
    float invd = 1.f / fmaxf((float)(s1 - s0), 1.f);
    float r0 = ax * invd + zrv.x;
    float r1 = ay * invd + zrv.y;
    float r2 = az * invd + zrv.z;
    float r3 = aw * invd + zrv.w;
    if (MODE == 1 || MODE == 2) {
        r0 = (r0 - mv.x) * (gv.x * rsqrtf(vv2.x + 1e-5f)) + bv.x;
        r1 = (r1 - mv.y) * (gv.y * rsqrtf(vv2.y + 1e-5f)) + bv.y;
        r2 = (r2 - mv.z) * (gv.z * rsqrtf(vv2.z + 1e-5f)) + bv.z;
        r3 = (r3 - mv.w) * (gv.w * rsqrtf(vv2.w + 1e-5f)) + bv.w;
    }
    if (MODE == 0 || MODE == 1) {
        r0 = fmaxf(r0, 0.f); r1 = fmaxf(r1, 0.f);
        r2 = fmaxf(r2, 0.f); r3 = fmaxf(r3, 0.f);
    }
    *(float4*)&out[(long)wid * NOUT + li4] = make_float4(r0, r1, r2, r3);
}

// ---------------- host ----------------
extern "C" void kernel_launch(void* const* d_in, const int* in_sizes, int n_in,
                              void* d_out, int out_size, void* d_ws, size_t ws_size,
                              hipStream_t stream) {
    const float* x    = (const float*)d_in[0];
    const int*   ei   = (const int*)d_in[1];
    const float* w1l  = (const float*)d_in[2];
    const float* w1r  = (const float*)d_in[3];
    const float* b1   = (const float*)d_in[4];
    const float* wxl  = (const float*)d_in[5];
    const float* wxr  = (const float*)d_in[6];
    const float* bx   = (const float*)d_in[7];
    const float* w2l  = (const float*)d_in[8];
    const float* w2r  = (const float*)d_in[9];
    const float* b2   = (const float*)d_in[10];
    const float* bn3g = (const float*)d_in[11];
    const float* bn3b = (const float*)d_in[12];
    const float* bn3m = (const float*)d_in[13];
    const float* bn3v = (const float*)d_in[14];
    const float* bn2g = (const float*)d_in[15];
    const float* bn2b = (const float*)d_in[16];
    const float* bn2m = (const float*)d_in[17];
    const float* bn2v = (const float*)d_in[18];
    float* out = (float*)d_out;

    char* p = (char*)d_ws;
    auto alloc = [&](size_t bytes) -> void* {
        void* r = (void*)p;
        p += (bytes + 255) & ~(size_t)255;
        return r;
    };
    int*   flag   = (int*)alloc(4);
    int*   bcur   = (int*)alloc(8 * 4);
    int*   cursor = (int*)alloc((size_t)NNODES * 4);
    int*   offs   = (int*)alloc((size_t)(NNODES + 1) * 4);
    int*   bsums  = (int*)alloc(128 * 4);
    int*   csr    = (int*)alloc((size_t)NEDGES * 4);
    float* bufA   = (float*)alloc((size_t)NNODES * 64 * 4); // h (layer input)
    unsigned short* zl16 = (unsigned short*)alloc((size_t)NNODES * 64 * 2); // bf16 zl
    float* bufD   = (float*)alloc((size_t)NNODES * 64 * 4); // zr
    unsigned short* B1h = (unsigned short*)alloc(16384 * 2);
    unsigned short* B1l = (unsigned short*)alloc(16384 * 2);
    unsigned short* B2h = (unsigned short*)alloc(8192 * 2);
    unsigned short* B2l = (unsigned short*)alloc(8192 * 2);
    unsigned short* B3h = (unsigned short*)alloc(5120 * 2);
    unsigned short* B3l = (unsigned short*)alloc(5120 * 2);
    // pairs (13.4MB) aliases bufA (25.6MB): dead once scatter_fine completes,
    // bufA first written by combine layer 1 (stream-ordered after).
    int2* pairs = (int2*)bufA;

    hipMemsetAsync(cursor, 0, (size_t)NNODES * 4, stream);
    hipMemsetAsync(bcur, 0, 8 * 4, stream);
    detect_kernel<<<1, 64, 0, stream>>>(ei, flag);
    bucketize<<<782, 256, 0, stream>>>(ei, flag, pairs, bcur, cursor); // + hist
    prep_w<128, 64, 128><<<64, 256, 0, stream>>>(w1l, w1r, B1h, B1l);
    prep_w<64, 64, 128><<<32, 256, 0, stream>>>(wxl, wxr, B2h, B2l);
    prep_w<64, 40, 80><<<20, 256, 0, stream>>>(w2l, w2r, B3h, B3l);
    scan_bsum<<<98, 256, 0, stream>>>(cursor, bsums);
    scan_partials<<<1, 128, 0, stream>>>(bsums, 98);
    scan_write<<<98, 256, 0, stream>>>(cursor, bsums, offs, cursor);
    scatter_fine<<<2048, 256, 0, stream>>>(pairs, bcur, cursor, csr);

    const int GB = (NNODES + 63) / 64;   // 1563
    // layer 1: x[N,128] -> h1[N,64] (relu)
    gemm_mfma<128, 64, 128><<<GB, 256, 0, stream>>>(x, B1h, B1l, b1, zl16, bufD, NNODES);
    combine_kernel<64, 0><<<25000, 256, 0, stream>>>(zl16, bufD, offs, csr,
                                                     nullptr, nullptr, nullptr, nullptr, bufA);
    // layer 2: h1 -> h2[N,64] (bn3 + relu)
    gemm_mfma<64, 64, 128><<<GB, 256, 0, stream>>>(bufA, B2h, B2l, bx, zl16, bufD, NNODES);
    combine_kernel<64, 1><<<25000, 256, 0, stream>>>(zl16, bufD, offs, csr,
                                                     bn3g, bn3b, bn3m, bn3v, bufA);
    // layer 3: h2 -> out[N,40] (bn2)
    gemm_mfma<64, 40, 80><<<GB, 256, 0, stream>>>(bufA, B3h, B3l, b2, zl16, bufD, NNODES);
    combine_kernel<40, 2><<<25000, 256, 0, stream>>>(zl16, bufD, offs, csr,
                                                     bn2g, bn2b, bn2m, bn2v, out);
}

// Round 13
// 288.287 us; speedup vs baseline: 1.2615x; 1.2615x over previous
//
#include <hip/hip_runtime.h>

#define NNODES 100000
#define NEDGES 1600000
#define NBK    391        // buckets of 256 nodes: bk = d >> 8
#define BK_CAP 4800       // mean 4092, sigma ~64 -> +11 sigma

typedef short bhalf8 __attribute__((ext_vector_type(8)));   // 8 bf16 bit patterns
typedef float f32x4 __attribute__((ext_vector_type(4)));

__device__ __forceinline__ unsigned fbits(float x){ union{float f;unsigned u;}c; c.f=x; return c.u; }
__device__ __forceinline__ float bcast(unsigned u){ union{float f;unsigned u;}c; c.u=u; return c.f; }
// round-to-nearest-even bf16 (top 16 bits of fp32)
__device__ __forceinline__ unsigned short rtn16(float x){
    unsigned u = fbits(x);
    return (unsigned short)((u + 0x7FFFu + ((u >> 16) & 1u)) >> 16);
}
__device__ __forceinline__ float b2f(unsigned short b){ return bcast((unsigned)b << 16); }

// ---------------- edge dtype detect: int64 vs int32 ----------------
__global__ void detect_kernel(const int* __restrict__ ei, int* __restrict__ flag) {
    int t = threadIdx.x;                 // 0..63
    int v = ei[2 * t + 1];
    unsigned long long nz = __ballot(v != 0);
    if (t == 0) flag[0] = (nz == 0ULL) ? 1 : 0;   // 1 => int64 layout
}

// ---------------- bucketize: ei -> 391 node-range buckets of (s,d) pairs ----
// LDS count (391 counters: ~1 collision/wave-step) + block reservation (~300K
// global atomics over 391 addrs). NO degree histogram, no random atomics.
__global__ __launch_bounds__(256) void bucketize(
    const int* __restrict__ ei, const int* __restrict__ flag,
    int2* __restrict__ pairs, int* __restrict__ bcur) {
    const int is64 = flag[0];
    __shared__ int cnt[NBK], base[NBK], rnk[NBK];
    int t = threadIdx.x;
    for (long start = (long)blockIdx.x * 1024; start < NEDGES;
         start += (long)gridDim.x * 1024) {
        __syncthreads();                 // protect prior iter's base/rnk
        for (int i = t; i < NBK; i += 256) { cnt[i] = 0; rnk[i] = 0; }
        __syncthreads();
        int sv[4], dv[4], bk[4];
#pragma unroll
        for (int k = 0; k < 4; ++k) {
            long e = start + k * 256 + t;
            bk[k] = -1;
            if (e < NEDGES) {
                sv[k] = is64 ? ei[2 * e] : ei[e];
                int d  = is64 ? ei[2 * (NEDGES + e)] : ei[NEDGES + e];
                dv[k] = d; bk[k] = d >> 8;
                atomicAdd(&cnt[bk[k]], 1);       // LDS, ~Poisson(0.65)/counter
            }
        }
        __syncthreads();
        for (int i = t; i < NBK; i += 256)
            if (cnt[i] > 0) base[i] = atomicAdd(&bcur[i], cnt[i]);
        __syncthreads();
#pragma unroll
        for (int k = 0; k < 4; ++k) {
            if (bk[k] >= 0) {
                int r = atomicAdd(&rnk[bk[k]], 1);   // LDS rank
                int pos = base[bk[k]] + r;
                if (pos < BK_CAP)                    // overflow guard (~0 prob)
                    pairs[(size_t)bk[k] * BK_CAP + pos] = make_int2(sv[k], dv[k]);
            }
        }
    }
}

// ---------------- csr_build: one block per bucket, zero global atomics ------
// Bucket = contiguous node range [b*256, b*256+256) -> contiguous csr slice.
// LDS histogram + LDS scan -> offs; LDS cursors -> dense csr scatter.
__global__ __launch_bounds__(512) void csr_build(
    const int2* __restrict__ pairs, const int* __restrict__ bcur,
    int* __restrict__ offs, int* __restrict__ csr) {
    const int b = blockIdx.x;          // 0..390
    const int t = threadIdx.x;         // 0..511
    const int lo = b << 8;
    __shared__ int sc[512];
    __shared__ int hist[256];
    __shared__ int loff[256];
    // exclusive prefix of bucket sizes -> global csr base (each block computes)
    sc[t] = (t < NBK) ? bcur[t] : 0;
    __syncthreads();
    for (int off = 1; off < 512; off <<= 1) {
        int other = (t >= off) ? sc[t - off] : 0;
        __syncthreads();
        sc[t] += other;
        __syncthreads();
    }
    const int n = bcur[b];
    const int csr_base = sc[b] - n;    // exclusive
    const int2* P = pairs + (size_t)b * BK_CAP;
    if (t < 256) hist[t] = 0;
    __syncthreads();
    for (int i = t; i < n; i += 512)
        atomicAdd(&hist[P[i].y & 255], 1);       // LDS, 256 counters
    __syncthreads();
    if (t < 256) sc[t] = hist[t];
    __syncthreads();
    for (int off = 1; off < 256; off <<= 1) {
        int other = (t >= off && t < 256) ? sc[t - off] : 0;
        __syncthreads();
        if (t < 256) sc[t] += other;
        __syncthreads();
    }
    if (t < 256) {
        int ex = sc[t] - hist[t];                // exclusive local offset
        loff[t] = ex;
        int node = lo + t;
        if (node < NNODES) offs[node] = csr_base + ex;
    }
    if (b == NBK - 1 && t == 0) offs[NNODES] = NEDGES;
    __syncthreads();
    if (t < 256) hist[t] = loff[t];              // reuse hist as cursor
    __syncthreads();
    for (int i = t; i < n; i += 512) {
        int2 p = P[i];
        int r = atomicAdd(&hist[p.y & 255], 1);  // LDS cursor
        csr[csr_base + r] = p.x;
    }
}

// ---------------- weight prep: fp32 -> bf16 2-way split (RTN) in B-frag order
template <int K, int NL, int NTOT>
__global__ void prep_w(const float* __restrict__ wl, const float* __restrict__ wr,
                       unsigned short* __restrict__ Bh, unsigned short* __restrict__ Bl) {
    constexpr int NCT = NTOT / 16;
    constexpr int TOT = (K / 32) * NCT * 512;
    for (int idx = blockIdx.x * blockDim.x + threadIdx.x; idx < TOT;
         idx += gridDim.x * blockDim.x) {
        int e = idx & 7, l = (idx >> 3) & 63, rest = idx >> 9;
        int ct = rest % NCT, kc = rest / NCT;
        int k = kc * 32 + (l >> 4) * 8 + e;
        int j = ct * 16 + (l & 15);
        float v = (j < NL) ? wl[k * NL + j] : wr[k * NL + (j - NL)];
        unsigned short h = rtn16(v);
        float r1 = v - bcast((unsigned)h << 16);    // exact residual
        Bh[idx] = h;
        Bl[idx] = rtn16(r1);
    }
}

// ---------------- MFMA dual GEMM: Z = h @ [wl|wr], 2-way RTN split, 3 MFMA
template <int K, int NL, int NTOT>
__global__ __launch_bounds__(256) void gemm_mfma(
    const float* __restrict__ h, const unsigned short* __restrict__ Bh,
    const unsigned short* __restrict__ Bl, const float* __restrict__ bias,
    unsigned short* __restrict__ zl, float* __restrict__ zr, int nrows) {
    constexpr int NCT = NTOT / 16;
    constexpr int NKC = K / 32;
    int t = threadIdx.x;
    int l = t & 63, w = t >> 6;
    int rb = blockIdx.x * 64 + w * 16;
    int arow = rb + (l & 15);
    int kg = l >> 4;
    f32x4 acc[NCT];
#pragma unroll
    for (int ct = 0; ct < NCT; ++ct) acc[ct] = (f32x4){0.f, 0.f, 0.f, 0.f};
    const bool aok = (arow < nrows);
    const float* hrow = h + (long)arow * K + kg * 8;
#pragma unroll
    for (int kc = 0; kc < NKC; ++kc) {
        float4 a0 = make_float4(0.f, 0.f, 0.f, 0.f), a1 = a0;
        if (aok) {
            a0 = *(const float4*)(hrow + kc * 32);
            a1 = *(const float4*)(hrow + kc * 32 + 4);
        }
        float av[8] = {a0.x, a0.y, a0.z, a0.w, a1.x, a1.y, a1.z, a1.w};
        bhalf8 ah, al;
#pragma unroll
        for (int e = 0; e < 8; ++e) {
            unsigned short hh = rtn16(av[e]);
            float r1 = av[e] - bcast((unsigned)hh << 16);
            ah[e] = (short)hh;
            al[e] = (short)rtn16(r1);
        }
        const unsigned short* hp = Bh + (size_t)(kc * NCT) * 512 + l * 8;
        const unsigned short* lp = Bl + (size_t)(kc * NCT) * 512 + l * 8;
#pragma unroll
        for (int ct = 0; ct < NCT; ++ct) {
            bhalf8 bh = *(const bhalf8*)(hp + ct * 512);
            bhalf8 bl = *(const bhalf8*)(lp + ct * 512);
            acc[ct] = __builtin_amdgcn_mfma_f32_16x16x32_bf16(ah, bh, acc[ct], 0, 0, 0);
            acc[ct] = __builtin_amdgcn_mfma_f32_16x16x32_bf16(ah, bl, acc[ct], 0, 0, 0);
            acc[ct] = __builtin_amdgcn_mfma_f32_16x16x32_bf16(al, bh, acc[ct], 0, 0, 0);
        }
    }
    // D: col = l&15, row = rb + (l>>4)*4 + r   [m89-verified]
    int orow0 = rb + kg * 4;
#pragma unroll
    for (int ct = 0; ct < NCT; ++ct) {
        int j = ct * 16 + (l & 15);
        bool isl = (j < NL);
        int cc = isl ? j : j - NL;
        float bj = isl ? 0.f : bias[cc];
#pragma unroll
        for (int r = 0; r < 4; ++r) {
            int orow = orow0 + r;
            if (orow < nrows) {
                if (isl) zl[(long)orow * NL + cc] = rtn16(acc[ct][r]);
                else     zr[(long)orow * NL + cc] = acc[ct][r] + bj;
            }
        }
    }
}

// ---------------- aggregate + combine + epilogue ----------------
// bf16 zl gather (128B rows), float4-wide columns per 16-lane group, 4 edge
// slots (q); __shfl always convergent (clamped source, unconditional).
// MODE: 0=relu,1=bn+relu,2=bn
template <int NOUT, int MODE>
__global__ __launch_bounds__(256) void combine_kernel(
    const unsigned short* __restrict__ zl, const float* __restrict__ zr,
    const int* __restrict__ offs, const int* __restrict__ csr,
    const float* __restrict__ g, const float* __restrict__ bb,
    const float* __restrict__ m, const float* __restrict__ v,
    float* __restrict__ out) {
    int wid  = (blockIdx.x * blockDim.x + threadIdx.x) >> 6;
    int lane = threadIdx.x & 63;
    if (wid >= NNODES) return;          // wave-uniform
    int q   = lane >> 4;            // edge slot 0..3
    int li4 = (lane & 15) * 4;      // column group
    const bool cok = (li4 < NOUT);
    // hoisted epilogue loads (independent of the gather chain)
    float4 zrv = make_float4(0.f, 0.f, 0.f, 0.f);
    float4 gv = zrv, bv = zrv, mv = zrv, vv2 = zrv;
    if (cok) {
        zrv = *(const float4*)&zr[(long)wid * NOUT + li4];
        if (MODE == 1 || MODE == 2) {
            gv  = *(const float4*)&g[li4];
            bv  = *(const float4*)&bb[li4];
            mv  = *(const float4*)&m[li4];
            vv2 = *(const float4*)&v[li4];
        }
    }
    int s0 = offs[wid], s1 = offs[wid + 1];
    float ax = 0.f, ay = 0.f, az = 0.f, aw = 0.f;
    for (int base = s0; base < s1; base += 64) {   // uniform bounds
        int c = min(64, s1 - base);                // >= 1 here
        int cm1 = c - 1;
        int sv = (base + lane < s1) ? csr[base + lane] : 0;
        for (int p0 = 0; p0 < c; p0 += 32) {       // uniform
            ushort4 hv[8];
            bool okk[8];
#pragma unroll
            for (int j = 0; j < 8; ++j) {
                int eidx = p0 + 4 * j + q;
                okk[j] = (eidx < c);
                int srow = __shfl(sv, min(eidx, cm1));   // all lanes, convergent
                ushort4 tv = make_ushort4(0, 0, 0, 0);
                if (cok) tv = *(const ushort4*)&zl[(long)srow * NOUT + li4];
                hv[j] = tv;
            }
#pragma unroll
            for (int j = 0; j < 8; ++j) {
                if (okk[j]) {
                    ax += b2f(hv[j].x); ay += b2f(hv[j].y);
                    az += b2f(hv[j].z); aw += b2f(hv[j].w);
                }
            }
        }
    }
    // reduce across the 4 edge slots — all 64 lanes participate (convergent)
    ax += __shfl_xor(ax, 16); ay += __shfl_xor(ay, 16);
    az += __shfl_xor(az, 16); aw += __shfl_xor(aw, 16);
    ax += __shfl_xor(ax, 32); ay += __shfl_xor(ay, 32);
    az += __shfl_xor(az, 32); aw += __shfl_xor(aw, 32);
    if (q != 0 || !cok) return;
    float invd = 1.f / fmaxf((float)(s1 - s0), 1.f);
    float r0 = ax * invd + zrv.x;
    float r1 = ay * invd + zrv.y;
    float r2 = az * invd + zrv.z;
    float r3 = aw * invd + zrv.w;
    if (MODE == 1 || MODE == 2) {
        r0 = (r0 - mv.x) * (gv.x * rsqrtf(vv2.x + 1e-5f)) + bv.x;
        r1 = (r1 - mv.y) * (gv.y * rsqrtf(vv2.y + 1e-5f)) + bv.y;
        r2 = (r2 - mv.z) * (gv.z * rsqrtf(vv2.z + 1e-5f)) + bv.z;
        r3 = (r3 - mv.w) * (gv.w * rsqrtf(vv2.w + 1e-5f)) + bv.w;
    }
    if (MODE == 0 || MODE == 1) {
        r0 = fmaxf(r0, 0.f); r1 = fmaxf(r1, 0.f);
        r2 = fmaxf(r2, 0.f); r3 = fmaxf(r3, 0.f);
    }
    *(float4*)&out[(long)wid * NOUT + li4] = make_float4(r0, r1, r2, r3);
}

// ---------------- host ----------------
extern "C" void kernel_launch(void* const* d_in, const int* in_sizes, int n_in,
                              void* d_out, int out_size, void* d_ws, size_t ws_size,
                              hipStream_t stream) {
    const float* x    = (const float*)d_in[0];
    const int*   ei   = (const int*)d_in[1];
    const float* w1l  = (const float*)d_in[2];
    const float* w1r  = (const float*)d_in[3];
    const float* b1   = (const float*)d_in[4];
    const float* wxl  = (const float*)d_in[5];
    const float* wxr  = (const float*)d_in[6];
    const float* bx   = (const float*)d_in[7];
    const float* w2l  = (const float*)d_in[8];
    const float* w2r  = (const float*)d_in[9];
    const float* b2   = (const float*)d_in[10];
    const float* bn3g = (const float*)d_in[11];
    const float* bn3b = (const float*)d_in[12];
    const float* bn3m = (const float*)d_in[13];
    const float* bn3v = (const float*)d_in[14];
    const float* bn2g = (const float*)d_in[15];
    const float* bn2b = (const float*)d_in[16];
    const float* bn2m = (const float*)d_in[17];
    const float* bn2v = (const float*)d_in[18];
    float* out = (float*)d_out;

    char* p = (char*)d_ws;
    auto alloc = [&](size_t bytes) -> void* {
        void* r = (void*)p;
        p += (bytes + 255) & ~(size_t)255;
        return r;
    };
    int*   flag   = (int*)alloc(4);
    int*   bcur   = (int*)alloc(NBK * 4);
    int*   offs   = (int*)alloc((size_t)(NNODES + 1) * 4);
    int*   csr    = (int*)alloc((size_t)NEDGES * 4);
    float* bufA   = (float*)alloc((size_t)NNODES * 64 * 4); // h (layer input)
    unsigned short* zl16 = (unsigned short*)alloc((size_t)NNODES * 64 * 2); // bf16 zl
    float* bufD   = (float*)alloc((size_t)NNODES * 64 * 4); // zr
    unsigned short* B1h = (unsigned short*)alloc(16384 * 2);
    unsigned short* B1l = (unsigned short*)alloc(16384 * 2);
    unsigned short* B2h = (unsigned short*)alloc(8192 * 2);
    unsigned short* B2l = (unsigned short*)alloc(8192 * 2);
    unsigned short* B3h = (unsigned short*)alloc(5120 * 2);
    unsigned short* B3l = (unsigned short*)alloc(5120 * 2);
    // pairs (391*4800*8B = 15.0MB) aliases bufA (25.6MB): dead after csr_build,
    // bufA first written by combine layer 1 (stream-ordered after).
    int2* pairs = (int2*)bufA;

    hipMemsetAsync(bcur, 0, NBK * 4, stream);
    detect_kernel<<<1, 64, 0, stream>>>(ei, flag);
    bucketize<<<1563, 256, 0, stream>>>(ei, flag, pairs, bcur);
    prep_w<128, 64, 128><<<64, 256, 0, stream>>>(w1l, w1r, B1h, B1l);
    prep_w<64, 64, 128><<<32, 256, 0, stream>>>(wxl, wxr, B2h, B2l);
    prep_w<64, 40, 80><<<20, 256, 0, stream>>>(w2l, w2r, B3h, B3l);
    csr_build<<<NBK, 512, 0, stream>>>(pairs, bcur, offs, csr);

    const int GB = (NNODES + 63) / 64;   // 1563
    // layer 1: x[N,128] -> h1[N,64] (relu)
    gemm_mfma<128, 64, 128><<<GB, 256, 0, stream>>>(x, B1h, B1l, b1, zl16, bufD, NNODES);
    combine_kernel<64, 0><<<25000, 256, 0, stream>>>(zl16, bufD, offs, csr,
                                                     nullptr, nullptr, nullptr, nullptr, bufA);
    // layer 2: h1 -> h2[N,64] (bn3 + relu)
    gemm_mfma<64, 64, 128><<<GB, 256, 0, stream>>>(bufA, B2h, B2l, bx, zl16, bufD, NNODES);
    combine_kernel<64, 1><<<25000, 256, 0, stream>>>(zl16, bufD, offs, csr,
                                                     bn3g, bn3b, bn3m, bn3v, bufA);
    // layer 3: h2 -> out[N,40] (bn2)
    gemm_mfma<64, 40, 80><<<GB, 256, 0, stream>>>(bufA, B3h, B3l, b2, zl16, bufD, NNODES);
    combine_kernel<40, 2><<<25000, 256, 0, stream>>>(zl16, bufD, offs, csr,
                                                     bn2g, bn2b, bn2m, bn2v, out);
}

// Round 14
// 253.309 us; speedup vs baseline: 1.4357x; 1.1381x over previous
//
#include <hip/hip_runtime.h>

#define NNODES 100000
#define NEDGES 1600000
#define NBK    196        // buckets of 512 nodes: bk = d >> 9
#define BK_CAP 9000       // mean 8163, sigma ~90 -> +9 sigma
#define CHUNK  4096

typedef short bhalf8 __attribute__((ext_vector_type(8)));   // 8 bf16 bit patterns
typedef float f32x4 __attribute__((ext_vector_type(4)));

__device__ __forceinline__ unsigned fbits(float x){ union{float f;unsigned u;}c; c.f=x; return c.u; }
__device__ __forceinline__ float bcast(unsigned u){ union{float f;unsigned u;}c; c.u=u; return c.f; }
// round-to-nearest-even bf16 (top 16 bits of fp32)
__device__ __forceinline__ unsigned short rtn16(float x){
    unsigned u = fbits(x);
    return (unsigned short)((u + 0x7FFFu + ((u >> 16) & 1u)) >> 16);
}
__device__ __forceinline__ float b2f(unsigned short b){ return bcast((unsigned)b << 16); }

// ---------------- edge dtype detect: int64 vs int32 ----------------
__global__ void detect_kernel(const int* __restrict__ ei, int* __restrict__ flag) {
    int t = threadIdx.x;                 // 0..63
    int v = ei[2 * t + 1];
    unsigned long long nz = __ballot(v != 0);
    if (t == 0) flag[0] = (nz == 0ULL) ? 1 : 0;   // 1 => int64 layout
}

// ---------------- bucketize: ei -> 196 node-range buckets of packed recs ----
// Per 4096-edge chunk: LDS count -> scan -> bucket-ordered LDS staging ->
// one reservation/bucket -> COALESCED flush (~84B per bucket per chunk).
// rec = (src << 9) | (dst & 511); 4 bytes. Zero random global atomics.
__global__ __launch_bounds__(256) void bucketize(
    const int* __restrict__ ei, const int* __restrict__ flag,
    unsigned* __restrict__ recs, int* __restrict__ bcur) {
    const int is64 = flag[0];
    __shared__ int cnt[256], base[256], loc[256], rnk[256];
    __shared__ unsigned stage[CHUNK];
    __shared__ unsigned char bkof[CHUNK];
    const int t = threadIdx.x;
    const long start = (long)blockIdx.x * CHUNK;
    cnt[t] = 0; rnk[t] = 0;
    __syncthreads();
    // pass A: count dst buckets
#pragma unroll
    for (int k = 0; k < CHUNK / 256; ++k) {
        long e = start + k * 256 + t;
        if (e < NEDGES) {
            int d = is64 ? ei[2 * (NEDGES + e)] : ei[NEDGES + e];
            atomicAdd(&cnt[d >> 9], 1);
        }
    }
    __syncthreads();
    // exclusive scan of cnt -> loc; reserve global space per bucket
    int v = cnt[t];
    int run = v;
    loc[t] = run;
    __syncthreads();
    for (int off = 1; off < 256; off <<= 1) {
        int other = (t >= off) ? loc[t - off] : 0;
        __syncthreads();
        run += other;
        loc[t] = run;
        __syncthreads();
    }
    int excl = run - v;
    if (v > 0) base[t] = atomicAdd(&bcur[t], v);
    loc[t] = excl;
    __syncthreads();
    // pass B: re-read edges (L2-hot), stage bucket-ordered
#pragma unroll
    for (int k = 0; k < CHUNK / 256; ++k) {
        long e = start + k * 256 + t;
        if (e < NEDGES) {
            int s = is64 ? ei[2 * e] : ei[e];
            int d = is64 ? ei[2 * (NEDGES + e)] : ei[NEDGES + e];
            int b = d >> 9;
            int r = atomicAdd(&rnk[b], 1);
            int pos = loc[b] + r;
            stage[pos] = ((unsigned)s << 9) | (unsigned)(d & 511);
            bkof[pos] = (unsigned char)b;
        }
    }
    __syncthreads();
    // flush: consecutive staged elems of a bucket -> consecutive global addrs
    const int tot = (int)min((long)CHUNK, NEDGES - start);
    for (int i = t; i < tot; i += 256) {
        int b = bkof[i];
        int pos = base[b] + (i - loc[b]);
        if (pos < BK_CAP)
            recs[(size_t)b * BK_CAP + pos] = stage[i];
    }
}

// ---------------- csr_build: one block per bucket, zero global atomics ------
// Bucket = node range [b*512, b*512+512) -> contiguous csr slice.
// LDS histogram + LDS scan -> offs; LDS cursors -> dense csr scatter.
__global__ __launch_bounds__(512) void csr_build(
    const unsigned* __restrict__ recs, const int* __restrict__ bcur,
    int* __restrict__ offs, int* __restrict__ csr) {
    const int b = blockIdx.x;          // 0..195
    const int t = threadIdx.x;         // 0..511
    const int lo = b << 9;
    __shared__ int sc[512];
    __shared__ int hist[512];
    __shared__ int loff[512];
    // exclusive prefix of bucket sizes -> global csr base
    int bv = (t < NBK) ? bcur[t] : 0;
    int run = bv;
    sc[t] = run;
    __syncthreads();
    for (int off = 1; off < 512; off <<= 1) {
        int other = (t >= off) ? sc[t - off] : 0;
        __syncthreads();
        run += other;
        sc[t] = run;
        __syncthreads();
    }
    const int n = bcur[b];
    const int csr_base = sc[b] - n;    // exclusive
    const unsigned* P = recs + (size_t)b * BK_CAP;
    hist[t] = 0;
    __syncthreads();
    for (int i = t; i < n; i += 512)
        atomicAdd(&hist[P[i] & 511], 1);         // LDS, 512 counters
    __syncthreads();
    int hv = hist[t];
    int hrun = hv;
    sc[t] = hrun;
    __syncthreads();
    for (int off = 1; off < 512; off <<= 1) {
        int other = (t >= off) ? sc[t - off] : 0;
        __syncthreads();
        hrun += other;
        sc[t] = hrun;
        __syncthreads();
    }
    int ex = hrun - hv;                          // exclusive local offset
    loff[t] = ex;
    int node = lo + t;
    if (node < NNODES) offs[node] = csr_base + ex;
    if (b == NBK - 1 && t == 0) offs[NNODES] = NEDGES;
    __syncthreads();
    hist[t] = loff[t];                           // reuse hist as cursor
    __syncthreads();
    for (int i = t; i < n; i += 512) {
        unsigned rec = P[i];
        int r = atomicAdd(&hist[rec & 511], 1);  // LDS cursor
        csr[csr_base + r] = (int)(rec >> 9);
    }
}

// ---------------- weight prep: fp32 -> bf16 2-way split (RTN) in B-frag order
template <int K, int NL, int NTOT>
__global__ void prep_w(const float* __restrict__ wl, const float* __restrict__ wr,
                       unsigned short* __restrict__ Bh, unsigned short* __restrict__ Bl) {
    constexpr int NCT = NTOT / 16;
    constexpr int TOT = (K / 32) * NCT * 512;
    for (int idx = blockIdx.x * blockDim.x + threadIdx.x; idx < TOT;
         idx += gridDim.x * blockDim.x) {
        int e = idx & 7, l = (idx >> 3) & 63, rest = idx >> 9;
        int ct = rest % NCT, kc = rest / NCT;
        int k = kc * 32 + (l >> 4) * 8 + e;
        int j = ct * 16 + (l & 15);
        float v = (j < NL) ? wl[k * NL + j] : wr[k * NL + (j - NL)];
        unsigned short h = rtn16(v);
        float r1 = v - bcast((unsigned)h << 16);    // exact residual
        Bh[idx] = h;
        Bl[idx] = rtn16(r1);
    }
}

// ---------------- MFMA dual GEMM: Z = h @ [wl|wr], 2-way RTN split, 3 MFMA
template <int K, int NL, int NTOT>
__global__ __launch_bounds__(256) void gemm_mfma(
    const float* __restrict__ h, const unsigned short* __restrict__ Bh,
    const unsigned short* __restrict__ Bl, const float* __restrict__ bias,
    unsigned short* __restrict__ zl, float* __restrict__ zr, int nrows) {
    constexpr int NCT = NTOT / 16;
    constexpr int NKC = K / 32;
    int t = threadIdx.x;
    int l = t & 63, w = t >> 6;
    int rb = blockIdx.x * 64 + w * 16;
    int arow = rb + (l & 15);
    int kg = l >> 4;
    f32x4 acc[NCT];
#pragma unroll
    for (int ct = 0; ct < NCT; ++ct) acc[ct] = (f32x4){0.f, 0.f, 0.f, 0.f};
    const bool aok = (arow < nrows);
    const float* hrow = h + (long)arow * K + kg * 8;
#pragma unroll
    for (int kc = 0; kc < NKC; ++kc) {
        float4 a0 = make_float4(0.f, 0.f, 0.f, 0.f), a1 = a0;
        if (aok) {
            a0 = *(const float4*)(hrow + kc * 32);
            a1 = *(const float4*)(hrow + kc * 32 + 4);
        }
        float av[8] = {a0.x, a0.y, a0.z, a0.w, a1.x, a1.y, a1.z, a1.w};
        bhalf8 ah, al;
#pragma unroll
        for (int e = 0; e < 8; ++e) {
            unsigned short hh = rtn16(av[e]);
            float r1 = av[e] - bcast((unsigned)hh << 16);
            ah[e] = (short)hh;
            al[e] = (short)rtn16(r1);
        }
        const unsigned short* hp = Bh + (size_t)(kc * NCT) * 512 + l * 8;
        const unsigned short* lp = Bl + (size_t)(kc * NCT) * 512 + l * 8;
#pragma unroll
        for (int ct = 0; ct < NCT; ++ct) {
            bhalf8 bh = *(const bhalf8*)(hp + ct * 512);
            bhalf8 bl = *(const bhalf8*)(lp + ct * 512);
            acc[ct] = __builtin_amdgcn_mfma_f32_16x16x32_bf16(ah, bh, acc[ct], 0, 0, 0);
            acc[ct] = __builtin_amdgcn_mfma_f32_16x16x32_bf16(ah, bl, acc[ct], 0, 0, 0);
            acc[ct] = __builtin_amdgcn_mfma_f32_16x16x32_bf16(al, bh, acc[ct], 0, 0, 0);
        }
    }
    // D: col = l&15, row = rb + (l>>4)*4 + r   [m89-verified]
    int orow0 = rb + kg * 4;
#pragma unroll
    for (int ct = 0; ct < NCT; ++ct) {
        int j = ct * 16 + (l & 15);
        bool isl = (j < NL);
        int cc = isl ? j : j - NL;
        float bj = isl ? 0.f : bias[cc];
#pragma unroll
        for (int r = 0; r < 4; ++r) {
            int orow = orow0 + r;
            if (orow < nrows) {
                if (isl) zl[(long)orow * NL + cc] = rtn16(acc[ct][r]);
                else     zr[(long)orow * NL + cc] = acc[ct][r] + bj;
            }
        }
    }
}

// ---------------- aggregate + combine + epilogue ----------------
// bf16 zl gather (128B rows), float4-wide columns per 16-lane group, 4 edge
// slots (q); __shfl always convergent (clamped source, unconditional).
// MODE: 0=relu,1=bn+relu,2=bn
template <int NOUT, int MODE>
__global__ __launch_bounds__(256) void combine_kernel(
    const unsigned short* __restrict__ zl, const float* __restrict__ zr,
    const int* __restrict__ offs, const int* __restrict__ csr,
    const float* __restrict__ g, const float* __restrict__ bb,
    const float* __restrict__ m, const float* __restrict__ v,
    float* __restrict__ out) {
    int wid  = (blockIdx.x * blockDim.x + threadIdx.x) >> 6;
    int lane = threadIdx.x & 63;
    if (wid >= NNODES) return;          // wave-uniform
    int q   = lane >> 4;            // edge slot 0..3
    int li4 = (lane & 15) * 4;      // column group
    const bool cok = (li4 < NOUT);
    // hoisted epilogue loads (independent of the gather chain)
    float4 zrv = make_float4(0.f, 0.f, 0.f, 0.f);
    float4 gv = zrv, bv = zrv, mv = zrv, vv2 = zrv;
    if (cok) {
        zrv = *(const float4*)&zr[(long)wid * NOUT + li4];
        if (MODE == 1 || MODE == 2) {
            gv  = *(const float4*)&g[li4];
            bv  = *(const float4*)&bb[li4];
            mv  = *(const float4*)&m[li4];
            vv2 = *(const float4*)&v[li4];
        }
    }
    int s0 = offs[wid], s1 = offs[wid + 1];
    float ax = 0.f, ay = 0.f, az = 0.f, aw = 0.f;
    for (int base = s0; base < s1; base += 64) {   // uniform bounds
        int c = min(64, s1 - base);                // >= 1 here
        int cm1 = c - 1;
        int sv = (base + lane < s1) ? csr[base + lane] : 0;
        for (int p0 = 0; p0 < c; p0 += 32) {       // uniform
            ushort4 hv[8];
            bool okk[8];
#pragma unroll
            for (int j = 0; j < 8; ++j) {
                int eidx = p0 + 4 * j + q;
                okk[j] = (eidx < c);
                int srow = __shfl(sv, min(eidx, cm1));   // all lanes, convergent
                ushort4 tv = make_ushort4(0, 0, 0, 0);
                if (cok) tv = *(const ushort4*)&zl[(long)srow * NOUT + li4];
                hv[j] = tv;
            }
#pragma unroll
            for (int j = 0; j < 8; ++j) {
                if (okk[j]) {
                    ax += b2f(hv[j].x); ay += b2f(hv[j].y);
                    az += b2f(hv[j].z); aw += b2f(hv[j].w);
                }
            }
        }
    }
    // reduce across the 4 edge slots — all 64 lanes participate (convergent)
    ax += __shfl_xor(ax, 16); ay += __shfl_xor(ay, 16);
    az += __shfl_xor(az, 16); aw += __shfl_xor(aw, 16);
    ax += __shfl_xor(ax, 32); ay += __shfl_xor(ay, 32);
    az += __shfl_xor(az, 32); aw += __shfl_xor(aw, 32);
    if (q != 0 || !cok) return;
    float invd = 1.f / fmaxf((float)(s1 - s0), 1.f);
    float r0 = ax * invd + zrv.x;
    float r1 = ay * invd + zrv.y;
    float r2 = az * invd + zrv.z;
    float r3 = aw * invd + zrv.w;
    if (MODE == 1 || MODE == 2) {
        r0 = (r0 - mv.x) * (gv.x * rsqrtf(vv2.x + 1e-5f)) + bv.x;
        r1 = (r1 - mv.y) * (gv.y * rsqrtf(vv2.y + 1e-5f)) + bv.y;
        r2 = (r2 - mv.z) * (gv.z * rsqrtf(vv2.z + 1e-5f)) + bv.z;
        r3 = (r3 - mv.w) * (gv.w * rsqrtf(vv2.w + 1e-5f)) + bv.w;
    }
    if (MODE == 0 || MODE == 1) {
        r0 = fmaxf(r0, 0.f); r1 = fmaxf(r1, 0.f);
        r2 = fmaxf(r2, 0.f); r3 = fmaxf(r3, 0.f);
    }
    *(float4*)&out[(long)wid * NOUT + li4] = make_float4(r0, r1, r2, r3);
}

// ---------------- host ----------------
extern "C" void kernel_launch(void* const* d_in, const int* in_sizes, int n_in,
                              void* d_out, int out_size, void* d_ws, size_t ws_size,
                              hipStream_t stream) {
    const float* x    = (const float*)d_in[0];
    const int*   ei   = (const int*)d_in[1];
    const float* w1l  = (const float*)d_in[2];
    const float* w1r  = (const float*)d_in[3];
    const float* b1   = (const float*)d_in[4];
    const float* wxl  = (const float*)d_in[5];
    const float* wxr  = (const float*)d_in[6];
    const float* bx   = (const float*)d_in[7];
    const float* w2l  = (const float*)d_in[8];
    const float* w2r  = (const float*)d_in[9];
    const float* b2   = (const float*)d_in[10];
    const float* bn3g = (const float*)d_in[11];
    const float* bn3b = (const float*)d_in[12];
    const float* bn3m = (const float*)d_in[13];
    const float* bn3v = (const float*)d_in[14];
    const float* bn2g = (const float*)d_in[15];
    const float* bn2b = (const float*)d_in[16];
    const float* bn2m = (const float*)d_in[17];
    const float* bn2v = (const float*)d_in[18];
    float* out = (float*)d_out;

    char* p = (char*)d_ws;
    auto alloc = [&](size_t bytes) -> void* {
        void* r = (void*)p;
        p += (bytes + 255) & ~(size_t)255;
        return r;
    };
    int*   flag   = (int*)alloc(4);
    int*   bcur   = (int*)alloc(NBK * 4);
    int*   offs   = (int*)alloc((size_t)(NNODES + 1) * 4);
    int*   csr    = (int*)alloc((size_t)NEDGES * 4);
    float* bufA   = (float*)alloc((size_t)NNODES * 64 * 4); // h (layer input)
    unsigned short* zl16 = (unsigned short*)alloc((size_t)NNODES * 64 * 2); // bf16 zl
    float* bufD   = (float*)alloc((size_t)NNODES * 64 * 4); // zr
    unsigned short* B1h = (unsigned short*)alloc(16384 * 2);
    unsigned short* B1l = (unsigned short*)alloc(16384 * 2);
    unsigned short* B2h = (unsigned short*)alloc(8192 * 2);
    unsigned short* B2l = (unsigned short*)alloc(8192 * 2);
    unsigned short* B3h = (unsigned short*)alloc(5120 * 2);
    unsigned short* B3l = (unsigned short*)alloc(5120 * 2);
    // recs (196*9000*4B = 7.1MB) aliases bufA (25.6MB): dead after csr_build,
    // bufA first written by combine layer 1 (stream-ordered after).
    unsigned* recs = (unsigned*)bufA;

    hipMemsetAsync(bcur, 0, NBK * 4, stream);
    detect_kernel<<<1, 64, 0, stream>>>(ei, flag);
    bucketize<<<(NEDGES + CHUNK - 1) / CHUNK, 256, 0, stream>>>(ei, flag, recs, bcur);
    prep_w<128, 64, 128><<<64, 256, 0, stream>>>(w1l, w1r, B1h, B1l);
    prep_w<64, 64, 128><<<32, 256, 0, stream>>>(wxl, wxr, B2h, B2l);
    prep_w<64, 40, 80><<<20, 256, 0, stream>>>(w2l, w2r, B3h, B3l);
    csr_build<<<NBK, 512, 0, stream>>>(recs, bcur, offs, csr);

    const int GB = (NNODES + 63) / 64;   // 1563
    // layer 1: x[N,128] -> h1[N,64] (relu)
    gemm_mfma<128, 64, 128><<<GB, 256, 0, stream>>>(x, B1h, B1l, b1, zl16, bufD, NNODES);
    combine_kernel<64, 0><<<25000, 256, 0, stream>>>(zl16, bufD, offs, csr,
                                                     nullptr, nullptr, nullptr, nullptr, bufA);
    // layer 2: h1 -> h2[N,64] (bn3 + relu)
    gemm_mfma<64, 64, 128><<<GB, 256, 0, stream>>>(bufA, B2h, B2l, bx, zl16, bufD, NNODES);
    combine_kernel<64, 1><<<25000, 256, 0, stream>>>(zl16, bufD, offs, csr,
                                                     bn3g, bn3b, bn3m, bn3v, bufA);
    // layer 3: h2 -> out[N,40] (bn2)
    gemm_mfma<64, 40, 80><<<GB, 256, 0, stream>>>(bufA, B3h, B3l, b2, zl16, bufD, NNODES);
    combine_kernel<40, 2><<<25000, 256, 0, stream>>>(zl16, bufD, offs, csr,
                                                     bn2g, bn2b, bn2m, bn2v, out);
}

// Round 15
// 240.221 us; speedup vs baseline: 1.5139x; 1.0545x over previous
//
#include <hip/hip_runtime.h>

#define NNODES 100000
#define NEDGES 1600000
#define NBK    196        // buckets of 512 nodes: bk = d >> 9
#define BK_CAP 9000       // mean 8163, sigma ~90 -> +9 sigma
#define CHUNK  4096

typedef short bhalf8 __attribute__((ext_vector_type(8)));   // 8 bf16 bit patterns
typedef float f32x4 __attribute__((ext_vector_type(4)));

__device__ __forceinline__ unsigned fbits(float x){ union{float f;unsigned u;}c; c.f=x; return c.u; }
__device__ __forceinline__ float bcast(unsigned u){ union{float f;unsigned u;}c; c.u=u; return c.f; }
// round-to-nearest-even bf16 (top 16 bits of fp32)
__device__ __forceinline__ unsigned short rtn16(float x){
    unsigned u = fbits(x);
    return (unsigned short)((u + 0x7FFFu + ((u >> 16) & 1u)) >> 16);
}
__device__ __forceinline__ float b2f(unsigned short b){ return bcast((unsigned)b << 16); }

// ---------------- edge dtype detect: int64 vs int32 ----------------
__global__ void detect_kernel(const int* __restrict__ ei, int* __restrict__ flag) {
    int t = threadIdx.x;                 // 0..63
    int v = ei[2 * t + 1];
    unsigned long long nz = __ballot(v != 0);
    if (t == 0) flag[0] = (nz == 0ULL) ? 1 : 0;   // 1 => int64 layout
}

// ---------------- bucketize: ei -> 196 node-range buckets of packed recs ----
// Per 4096-edge chunk: LDS count -> scan -> bucket-ordered LDS staging ->
// one reservation/bucket -> COALESCED flush. rec = (src<<9)|(dst&511).
__global__ __launch_bounds__(256) void bucketize(
    const int* __restrict__ ei, const int* __restrict__ flag,
    unsigned* __restrict__ recs, int* __restrict__ bcur) {
    const int is64 = flag[0];
    __shared__ int cnt[256], base[256], loc[256], rnk[256];
    __shared__ unsigned stage[CHUNK];
    __shared__ unsigned char bkof[CHUNK];
    const int t = threadIdx.x;
    const long start = (long)blockIdx.x * CHUNK;
    cnt[t] = 0; rnk[t] = 0;
    __syncthreads();
#pragma unroll
    for (int k = 0; k < CHUNK / 256; ++k) {
        long e = start + k * 256 + t;
        if (e < NEDGES) {
            int d = is64 ? ei[2 * (NEDGES + e)] : ei[NEDGES + e];
            atomicAdd(&cnt[d >> 9], 1);
        }
    }
    __syncthreads();
    int v = cnt[t];
    int run = v;
    loc[t] = run;
    __syncthreads();
    for (int off = 1; off < 256; off <<= 1) {
        int other = (t >= off) ? loc[t - off] : 0;
        __syncthreads();
        run += other;
        loc[t] = run;
        __syncthreads();
    }
    int excl = run - v;
    if (v > 0) base[t] = atomicAdd(&bcur[t], v);
    loc[t] = excl;
    __syncthreads();
#pragma unroll
    for (int k = 0; k < CHUNK / 256; ++k) {
        long e = start + k * 256 + t;
        if (e < NEDGES) {
            int s = is64 ? ei[2 * e] : ei[e];
            int d = is64 ? ei[2 * (NEDGES + e)] : ei[NEDGES + e];
            int b = d >> 9;
            int r = atomicAdd(&rnk[b], 1);
            int pos = loc[b] + r;
            stage[pos] = ((unsigned)s << 9) | (unsigned)(d & 511);
            bkof[pos] = (unsigned char)b;
        }
    }
    __syncthreads();
    const int tot = (int)min((long)CHUNK, NEDGES - start);
    for (int i = t; i < tot; i += 256) {
        int b = bkof[i];
        int pos = base[b] + (i - loc[b]);
        if (pos < BK_CAP)
            recs[(size_t)b * BK_CAP + pos] = stage[i];
    }
}

// ---------------- csr_build: one block per bucket, zero global atomics ------
__global__ __launch_bounds__(512) void csr_build(
    const unsigned* __restrict__ recs, const int* __restrict__ bcur,
    int* __restrict__ offs, int* __restrict__ csr) {
    const int b = blockIdx.x;          // 0..195
    const int t = threadIdx.x;         // 0..511
    const int lo = b << 9;
    __shared__ int sc[512];
    __shared__ int hist[512];
    __shared__ int loff[512];
    int bv = (t < NBK) ? bcur[t] : 0;
    int run = bv;
    sc[t] = run;
    __syncthreads();
    for (int off = 1; off < 512; off <<= 1) {
        int other = (t >= off) ? sc[t - off] : 0;
        __syncthreads();
        run += other;
        sc[t] = run;
        __syncthreads();
    }
    const int n = bcur[b];
    const int csr_base = sc[b] - n;    // exclusive
    const unsigned* P = recs + (size_t)b * BK_CAP;
    hist[t] = 0;
    __syncthreads();
    for (int i = t; i < n; i += 512)
        atomicAdd(&hist[P[i] & 511], 1);
    __syncthreads();
    int hv = hist[t];
    int hrun = hv;
    sc[t] = hrun;
    __syncthreads();
    for (int off = 1; off < 512; off <<= 1) {
        int other = (t >= off) ? sc[t - off] : 0;
        __syncthreads();
        hrun += other;
        sc[t] = hrun;
        __syncthreads();
    }
    int ex = hrun - hv;
    loff[t] = ex;
    int node = lo + t;
    if (node < NNODES) offs[node] = csr_base + ex;
    if (b == NBK - 1 && t == 0) offs[NNODES] = NEDGES;
    __syncthreads();
    hist[t] = loff[t];
    __syncthreads();
    for (int i = t; i < n; i += 512) {
        unsigned rec = P[i];
        int r = atomicAdd(&hist[rec & 511], 1);
        csr[csr_base + r] = (int)(rec >> 9);
    }
}

// ---------------- weight prep: fp32 -> bf16 2-way split (RTN) in B-frag order
template <int K, int NL, int NTOT>
__global__ void prep_w(const float* __restrict__ wl, const float* __restrict__ wr,
                       unsigned short* __restrict__ Bh, unsigned short* __restrict__ Bl) {
    constexpr int NCT = NTOT / 16;
    constexpr int TOT = (K / 32) * NCT * 512;
    for (int idx = blockIdx.x * blockDim.x + threadIdx.x; idx < TOT;
         idx += gridDim.x * blockDim.x) {
        int e = idx & 7, l = (idx >> 3) & 63, rest = idx >> 9;
        int ct = rest % NCT, kc = rest / NCT;
        int k = kc * 32 + (l >> 4) * 8 + e;
        int j = ct * 16 + (l & 15);
        float v = (j < NL) ? wl[k * NL + j] : wr[k * NL + (j - NL)];
        unsigned short h = rtn16(v);
        float r1 = v - bcast((unsigned)h << 16);    // exact residual
        Bh[idx] = h;
        Bl[idx] = rtn16(r1);
    }
}

// ---------------- MFMA dual GEMM: Z = h @ [wl|wr] ---------------------------
// ABF16=false: A fp32, 2-way RTN split, 3 MFMA (layer 1, x input).
// ABF16=true:  A already bf16 rows, exact, 2 MFMA (layers 2/3, h16 input).
// zl, zr both written bf16 (RTN).
template <int K, int NL, int NTOT, bool ABF16>
__global__ __launch_bounds__(256) void gemm_mfma(
    const void* __restrict__ hvp, const unsigned short* __restrict__ Bh,
    const unsigned short* __restrict__ Bl, const float* __restrict__ bias,
    unsigned short* __restrict__ zl, unsigned short* __restrict__ zr, int nrows) {
    constexpr int NCT = NTOT / 16;
    constexpr int NKC = K / 32;
    int t = threadIdx.x;
    int l = t & 63, w = t >> 6;
    int rb = blockIdx.x * 64 + w * 16;
    int arow = rb + (l & 15);
    int kg = l >> 4;
    f32x4 acc[NCT];
#pragma unroll
    for (int ct = 0; ct < NCT; ++ct) acc[ct] = (f32x4){0.f, 0.f, 0.f, 0.f};
    const bool aok = (arow < nrows);
#pragma unroll
    for (int kc = 0; kc < NKC; ++kc) {
        bhalf8 ah = {0,0,0,0,0,0,0,0}, al = {0,0,0,0,0,0,0,0};
        if (ABF16) {
            const unsigned short* hr =
                (const unsigned short*)hvp + (long)arow * K + kg * 8;
            if (aok) ah = *(const bhalf8*)(hr + kc * 32);
        } else {
            const float* hr = (const float*)hvp + (long)arow * K + kg * 8;
            float4 a0 = make_float4(0.f, 0.f, 0.f, 0.f), a1 = a0;
            if (aok) {
                a0 = *(const float4*)(hr + kc * 32);
                a1 = *(const float4*)(hr + kc * 32 + 4);
            }
            float av[8] = {a0.x, a0.y, a0.z, a0.w, a1.x, a1.y, a1.z, a1.w};
#pragma unroll
            for (int e = 0; e < 8; ++e) {
                unsigned short hh = rtn16(av[e]);
                float r1 = av[e] - bcast((unsigned)hh << 16);
                ah[e] = (short)hh;
                al[e] = (short)rtn16(r1);
            }
        }
        const unsigned short* hp = Bh + (size_t)(kc * NCT) * 512 + l * 8;
        const unsigned short* lp = Bl + (size_t)(kc * NCT) * 512 + l * 8;
#pragma unroll
        for (int ct = 0; ct < NCT; ++ct) {
            bhalf8 bh = *(const bhalf8*)(hp + ct * 512);
            bhalf8 bl = *(const bhalf8*)(lp + ct * 512);
            acc[ct] = __builtin_amdgcn_mfma_f32_16x16x32_bf16(ah, bh, acc[ct], 0, 0, 0);
            acc[ct] = __builtin_amdgcn_mfma_f32_16x16x32_bf16(ah, bl, acc[ct], 0, 0, 0);
            if (!ABF16)
                acc[ct] = __builtin_amdgcn_mfma_f32_16x16x32_bf16(al, bh, acc[ct], 0, 0, 0);
        }
    }
    // D: col = l&15, row = rb + (l>>4)*4 + r   [m89-verified]
    int orow0 = rb + kg * 4;
#pragma unroll
    for (int ct = 0; ct < NCT; ++ct) {
        int j = ct * 16 + (l & 15);
        bool isl = (j < NL);
        int cc = isl ? j : j - NL;
        float bj = isl ? 0.f : bias[cc];
        unsigned short* __restrict__ dp = isl ? zl : zr;
#pragma unroll
        for (int r = 0; r < 4; ++r) {
            int orow = orow0 + r;
            if (orow < nrows) dp[(long)orow * NL + cc] = rtn16(acc[ct][r] + bj);
        }
    }
}

// ---------------- aggregate + combine + epilogue ----------------
// bf16 zl gather (128B rows), float4-wide columns per 16-lane group, 4 edge
// slots (q); __shfl always convergent; LOADS predicated, adds unconditional.
// MODE 0/1 write bf16 h rows (OUTT=ushort); MODE 2 writes fp32 (OUTT=float).
template <int NOUT, int MODE, typename OUTT>
__global__ __launch_bounds__(256) void combine_kernel(
    const unsigned short* __restrict__ zl, const unsigned short* __restrict__ zr,
    const int* __restrict__ offs, const int* __restrict__ csr,
    const float* __restrict__ g, const float* __restrict__ bb,
    const float* __restrict__ m, const float* __restrict__ v,
    OUTT* __restrict__ out) {
    int wid  = (blockIdx.x * blockDim.x + threadIdx.x) >> 6;
    int lane = threadIdx.x & 63;
    if (wid >= NNODES) return;          // wave-uniform
    int q   = lane >> 4;            // edge slot 0..3
    int li4 = (lane & 15) * 4;      // column group
    const bool cok = (li4 < NOUT);
    // hoisted epilogue loads (independent of the gather chain)
    float4 zrv = make_float4(0.f, 0.f, 0.f, 0.f);
    float4 gv = zrv, bv = zrv, mv = zrv, vv2 = zrv;
    if (cok) {
        ushort4 zb = *(const ushort4*)&zr[(long)wid * NOUT + li4];
        zrv = make_float4(b2f(zb.x), b2f(zb.y), b2f(zb.z), b2f(zb.w));
        if (MODE == 1 || MODE == 2) {
            gv  = *(const float4*)&g[li4];
            bv  = *(const float4*)&bb[li4];
            mv  = *(const float4*)&m[li4];
            vv2 = *(const float4*)&v[li4];
        }
    }
    int s0 = offs[wid], s1 = offs[wid + 1];
    float ax = 0.f, ay = 0.f, az = 0.f, aw = 0.f;
    for (int base = s0; base < s1; base += 64) {   // uniform bounds
        int c = min(64, s1 - base);                // >= 1 here
        int cm1 = c - 1;
        int sv = (base + lane < s1) ? csr[base + lane] : 0;
        for (int p0 = 0; p0 < c; p0 += 32) {       // uniform
            ushort4 hv[8];
#pragma unroll
            for (int j = 0; j < 8; ++j) {
                int eidx = p0 + 4 * j + q;
                int srow = __shfl(sv, min(eidx, cm1));   // all lanes, convergent
                ushort4 tv = make_ushort4(0, 0, 0, 0);
                if (eidx < c && cok)                     // predicated LOAD only
                    tv = *(const ushort4*)&zl[(long)srow * NOUT + li4];
                hv[j] = tv;
            }
#pragma unroll
            for (int j = 0; j < 8; ++j) {                // unconditional adds
                ax += b2f(hv[j].x); ay += b2f(hv[j].y);
                az += b2f(hv[j].z); aw += b2f(hv[j].w);
            }
        }
    }
    // reduce across the 4 edge slots — all 64 lanes participate (convergent)
    ax += __shfl_xor(ax, 16); ay += __shfl_xor(ay, 16);
    az += __shfl_xor(az, 16); aw += __shfl_xor(aw, 16);
    ax += __shfl_xor(ax, 32); ay += __shfl_xor(ay, 32);
    az += __shfl_xor(az, 32); aw += __shfl_xor(aw, 32);
    if (q != 0 || !cok) return;
    float invd = 1.f / fmaxf((float)(s1 - s0), 1.f);
    float r0 = ax * invd + zrv.x;
    float r1 = ay * invd + zrv.y;
    float r2 = az * invd + zrv.z;
    float r3 = aw * invd + zrv.w;
    if (MODE == 1 || MODE == 2) {
        r0 = (r0 - mv.x) * (gv.x * rsqrtf(vv2.x + 1e-5f)) + bv.x;
        r1 = (r1 - mv.y) * (gv.y * rsqrtf(vv2.y + 1e-5f)) + bv.y;
        r2 = (r2 - mv.z) * (gv.z * rsqrtf(vv2.z + 1e-5f)) + bv.z;
        r3 = (r3 - mv.w) * (gv.w * rsqrtf(vv2.w + 1e-5f)) + bv.w;
    }
    if (MODE == 0 || MODE == 1) {
        r0 = fmaxf(r0, 0.f); r1 = fmaxf(r1, 0.f);
        r2 = fmaxf(r2, 0.f); r3 = fmaxf(r3, 0.f);
    }
    if constexpr (MODE == 2) {
        *(float4*)&out[(long)wid * NOUT + li4] = make_float4(r0, r1, r2, r3);
    } else {
        ushort4 o = make_ushort4(rtn16(r0), rtn16(r1), rtn16(r2), rtn16(r3));
        *(ushort4*)&out[(long)wid * NOUT + li4] = o;
    }
}

// ---------------- host ----------------
extern "C" void kernel_launch(void* const* d_in, const int* in_sizes, int n_in,
                              void* d_out, int out_size, void* d_ws, size_t ws_size,
                              hipStream_t stream) {
    const float* x    = (const float*)d_in[0];
    const int*   ei   = (const int*)d_in[1];
    const float* w1l  = (const float*)d_in[2];
    const float* w1r  = (const float*)d_in[3];
    const float* b1   = (const float*)d_in[4];
    const float* wxl  = (const float*)d_in[5];
    const float* wxr  = (const float*)d_in[6];
    const float* bx   = (const float*)d_in[7];
    const float* w2l  = (const float*)d_in[8];
    const float* w2r  = (const float*)d_in[9];
    const float* b2   = (const float*)d_in[10];
    const float* bn3g = (const float*)d_in[11];
    const float* bn3b = (const float*)d_in[12];
    const float* bn3m = (const float*)d_in[13];
    const float* bn3v = (const float*)d_in[14];
    const float* bn2g = (const float*)d_in[15];
    const float* bn2b = (const float*)d_in[16];
    const float* bn2m = (const float*)d_in[17];
    const float* bn2v = (const float*)d_in[18];
    float* out = (float*)d_out;

    char* p = (char*)d_ws;
    auto alloc = [&](size_t bytes) -> void* {
        void* r = (void*)p;
        p += (bytes + 255) & ~(size_t)255;
        return r;
    };
    int*   flag   = (int*)alloc(4);
    int*   bcur   = (int*)alloc(NBK * 4);
    int*   offs   = (int*)alloc((size_t)(NNODES + 1) * 4);
    int*   csr    = (int*)alloc((size_t)NEDGES * 4);
    unsigned short* h16  = (unsigned short*)alloc((size_t)NNODES * 64 * 2); // bf16 h
    unsigned short* zl16 = (unsigned short*)alloc((size_t)NNODES * 64 * 2); // bf16 zl
    unsigned short* zr16 = (unsigned short*)alloc((size_t)NNODES * 64 * 2); // bf16 zr
    unsigned short* B1h = (unsigned short*)alloc(16384 * 2);
    unsigned short* B1l = (unsigned short*)alloc(16384 * 2);
    unsigned short* B2h = (unsigned short*)alloc(8192 * 2);
    unsigned short* B2l = (unsigned short*)alloc(8192 * 2);
    unsigned short* B3h = (unsigned short*)alloc(5120 * 2);
    unsigned short* B3l = (unsigned short*)alloc(5120 * 2);
    // recs (196*9000*4B = 7.1MB) aliases h16 (12.8MB): dead after csr_build,
    // h16 first written by combine layer 1 (stream-ordered after).
    unsigned* recs = (unsigned*)h16;

    hipMemsetAsync(bcur, 0, NBK * 4, stream);
    detect_kernel<<<1, 64, 0, stream>>>(ei, flag);
    bucketize<<<(NEDGES + CHUNK - 1) / CHUNK, 256, 0, stream>>>(ei, flag, recs, bcur);
    prep_w<128, 64, 128><<<64, 256, 0, stream>>>(w1l, w1r, B1h, B1l);
    prep_w<64, 64, 128><<<32, 256, 0, stream>>>(wxl, wxr, B2h, B2l);
    prep_w<64, 40, 80><<<20, 256, 0, stream>>>(w2l, w2r, B3h, B3l);
    csr_build<<<NBK, 512, 0, stream>>>(recs, bcur, offs, csr);

    const int GB = (NNODES + 63) / 64;   // 1563
    // layer 1: x[N,128] (fp32) -> zl/zr -> h1 (bf16, relu)
    gemm_mfma<128, 64, 128, false><<<GB, 256, 0, stream>>>(x, B1h, B1l, b1, zl16, zr16, NNODES);
    combine_kernel<64, 0, unsigned short><<<25000, 256, 0, stream>>>(
        zl16, zr16, offs, csr, nullptr, nullptr, nullptr, nullptr, h16);
    // layer 2: h1 (bf16) -> zl/zr -> h2 (bf16, bn3+relu)
    gemm_mfma<64, 64, 128, true><<<GB, 256, 0, stream>>>(h16, B2h, B2l, bx, zl16, zr16, NNODES);
    combine_kernel<64, 1, unsigned short><<<25000, 256, 0, stream>>>(
        zl16, zr16, offs, csr, bn3g, bn3b, bn3m, bn3v, h16);
    // layer 3: h2 (bf16) -> zl/zr -> out (fp32, bn2)
    gemm_mfma<64, 40, 80, true><<<GB, 256, 0, stream>>>(h16, B3h, B3l, b2, zl16, zr16, NNODES);
    combine_kernel<40, 2, float><<<25000, 256, 0, stream>>>(
        zl16, zr16, offs, csr, bn2g, bn2b, bn2m, bn2v, out);
}

// Round 16
// 238.157 us; speedup vs baseline: 1.5271x; 1.0087x over previous
//
#include <hip/hip_runtime.h>

#define NNODES 100000
#define NEDGES 1600000
#define NBK    196        // buckets of 512 nodes: bk = d >> 9
#define BK_CAP 9000       // mean 8163, sigma ~90 -> +9 sigma
#define CHUNK  4096

typedef short bhalf8 __attribute__((ext_vector_type(8)));   // 8 bf16 bit patterns
typedef float f32x4 __attribute__((ext_vector_type(4)));

__device__ __forceinline__ unsigned fbits(float x){ union{float f;unsigned u;}c; c.f=x; return c.u; }
__device__ __forceinline__ float bcast(unsigned u){ union{float f;unsigned u;}c; c.u=u; return c.f; }
// round-to-nearest-even bf16 (top 16 bits of fp32)
__device__ __forceinline__ unsigned short rtn16(float x){
    unsigned u = fbits(x);
    return (unsigned short)((u + 0x7FFFu + ((u >> 16) & 1u)) >> 16);
}
__device__ __forceinline__ float b2f(unsigned short b){ return bcast((unsigned)b << 16); }

// ---------------- edge dtype detect: int64 vs int32 ----------------
__global__ void detect_kernel(const int* __restrict__ ei, int* __restrict__ flag) {
    int t = threadIdx.x;                 // 0..63
    int v = ei[2 * t + 1];
    unsigned long long nz = __ballot(v != 0);
    if (t == 0) flag[0] = (nz == 0ULL) ? 1 : 0;   // 1 => int64 layout
}

// ---------------- bucketize: ei -> 196 node-range buckets of packed recs ----
// Per 4096-edge chunk: LDS count -> scan -> bucket-ordered LDS staging ->
// one reservation/bucket -> COALESCED flush. rec = (src<<9)|(dst&511).
__global__ __launch_bounds__(256) void bucketize(
    const int* __restrict__ ei, const int* __restrict__ flag,
    unsigned* __restrict__ recs, int* __restrict__ bcur) {
    const int is64 = flag[0];
    __shared__ int cnt[256], base[256], loc[256], rnk[256];
    __shared__ unsigned stage[CHUNK];
    __shared__ unsigned char bkof[CHUNK];
    const int t = threadIdx.x;
    const long start = (long)blockIdx.x * CHUNK;
    cnt[t] = 0; rnk[t] = 0;
    __syncthreads();
#pragma unroll
    for (int k = 0; k < CHUNK / 256; ++k) {
        long e = start + k * 256 + t;
        if (e < NEDGES) {
            int d = is64 ? ei[2 * (NEDGES + e)] : ei[NEDGES + e];
            atomicAdd(&cnt[d >> 9], 1);
        }
    }
    __syncthreads();
    int v = cnt[t];
    int run = v;
    loc[t] = run;
    __syncthreads();
    for (int off = 1; off < 256; off <<= 1) {
        int other = (t >= off) ? loc[t - off] : 0;
        __syncthreads();
        run += other;
        loc[t] = run;
        __syncthreads();
    }
    int excl = run - v;
    if (v > 0) base[t] = atomicAdd(&bcur[t], v);
    loc[t] = excl;
    __syncthreads();
#pragma unroll
    for (int k = 0; k < CHUNK / 256; ++k) {
        long e = start + k * 256 + t;
        if (e < NEDGES) {
            int s = is64 ? ei[2 * e] : ei[e];
            int d = is64 ? ei[2 * (NEDGES + e)] : ei[NEDGES + e];
            int b = d >> 9;
            int r = atomicAdd(&rnk[b], 1);
            int pos = loc[b] + r;
            stage[pos] = ((unsigned)s << 9) | (unsigned)(d & 511);
            bkof[pos] = (unsigned char)b;
        }
    }
    __syncthreads();
    const int tot = (int)min((long)CHUNK, NEDGES - start);
    for (int i = t; i < tot; i += 256) {
        int b = bkof[i];
        int pos = base[b] + (i - loc[b]);
        if (pos < BK_CAP)
            recs[(size_t)b * BK_CAP + pos] = stage[i];
    }
}

// ---------------- csr_build: one block per bucket, zero global atomics ------
__global__ __launch_bounds__(512) void csr_build(
    const unsigned* __restrict__ recs, const int* __restrict__ bcur,
    int* __restrict__ offs, int* __restrict__ csr) {
    const int b = blockIdx.x;          // 0..195
    const int t = threadIdx.x;         // 0..511
    const int lo = b << 9;
    __shared__ int sc[512];
    __shared__ int hist[512];
    __shared__ int loff[512];
    int bv = (t < NBK) ? bcur[t] : 0;
    int run = bv;
    sc[t] = run;
    __syncthreads();
    for (int off = 1; off < 512; off <<= 1) {
        int other = (t >= off) ? sc[t - off] : 0;
        __syncthreads();
        run += other;
        sc[t] = run;
        __syncthreads();
    }
    const int n = bcur[b];
    const int csr_base = sc[b] - n;    // exclusive
    const unsigned* P = recs + (size_t)b * BK_CAP;
    hist[t] = 0;
    __syncthreads();
    for (int i = t; i < n; i += 512)
        atomicAdd(&hist[P[i] & 511], 1);
    __syncthreads();
    int hv = hist[t];
    int hrun = hv;
    sc[t] = hrun;
    __syncthreads();
    for (int off = 1; off < 512; off <<= 1) {
        int other = (t >= off) ? sc[t - off] : 0;
        __syncthreads();
        hrun += other;
        sc[t] = hrun;
        __syncthreads();
    }
    int ex = hrun - hv;
    loff[t] = ex;
    int node = lo + t;
    if (node < NNODES) offs[node] = csr_base + ex;
    if (b == NBK - 1 && t == 0) offs[NNODES] = NEDGES;
    __syncthreads();
    hist[t] = loff[t];
    __syncthreads();
    for (int i = t; i < n; i += 512) {
        unsigned rec = P[i];
        int r = atomicAdd(&hist[rec & 511], 1);
        csr[csr_base + r] = (int)(rec >> 9);
    }
}

// ---------------- weight prep: fp32 -> bf16 2-way split (RTN) in B-frag order
template <int K, int NL, int NTOT>
__global__ void prep_w(const float* __restrict__ wl, const float* __restrict__ wr,
                       unsigned short* __restrict__ Bh, unsigned short* __restrict__ Bl) {
    constexpr int NCT = NTOT / 16;
    constexpr int TOT = (K / 32) * NCT * 512;
    for (int idx = blockIdx.x * blockDim.x + threadIdx.x; idx < TOT;
         idx += gridDim.x * blockDim.x) {
        int e = idx & 7, l = (idx >> 3) & 63, rest = idx >> 9;
        int ct = rest % NCT, kc = rest / NCT;
        int k = kc * 32 + (l >> 4) * 8 + e;
        int j = ct * 16 + (l & 15);
        float v = (j < NL) ? wl[k * NL + j] : wr[k * NL + (j - NL)];
        unsigned short h = rtn16(v);
        float r1 = v - bcast((unsigned)h << 16);    // exact residual
        Bh[idx] = h;
        Bl[idx] = rtn16(r1);
    }
}

// ---------------- MFMA dual GEMM: Z = h @ [wl|wr] ---------------------------
// ABF16=false: A fp32, 2-way RTN split, 3 MFMA (layer 1, x input).
// ABF16=true:  A already bf16 rows, exact, 2 MFMA (layers 2/3, h16 input).
// zl, zr both written bf16 (RTN).
template <int K, int NL, int NTOT, bool ABF16>
__global__ __launch_bounds__(256) void gemm_mfma(
    const void* __restrict__ hvp, const unsigned short* __restrict__ Bh,
    const unsigned short* __restrict__ Bl, const float* __restrict__ bias,
    unsigned short* __restrict__ zl, unsigned short* __restrict__ zr, int nrows) {
    constexpr int NCT = NTOT / 16;
    constexpr int NKC = K / 32;
    int t = threadIdx.x;
    int l = t & 63, w = t >> 6;
    int rb = blockIdx.x * 64 + w * 16;
    int arow = rb + (l & 15);
    int kg = l >> 4;
    f32x4 acc[NCT];
#pragma unroll
    for (int ct = 0; ct < NCT; ++ct) acc[ct] = (f32x4){0.f, 0.f, 0.f, 0.f};
    const bool aok = (arow < nrows);
#pragma unroll
    for (int kc = 0; kc < NKC; ++kc) {
        bhalf8 ah = {0,0,0,0,0,0,0,0}, al = {0,0,0,0,0,0,0,0};
        if (ABF16) {
            const unsigned short* hr =
                (const unsigned short*)hvp + (long)arow * K + kg * 8;
            if (aok) ah = *(const bhalf8*)(hr + kc * 32);
        } else {
            const float* hr = (const float*)hvp + (long)arow * K + kg * 8;
            float4 a0 = make_float4(0.f, 0.f, 0.f, 0.f), a1 = a0;
            if (aok) {
                a0 = *(const float4*)(hr + kc * 32);
                a1 = *(const float4*)(hr + kc * 32 + 4);
            }
            float av[8] = {a0.x, a0.y, a0.z, a0.w, a1.x, a1.y, a1.z, a1.w};
#pragma unroll
            for (int e = 0; e < 8; ++e) {
                unsigned short hh = rtn16(av[e]);
                float r1 = av[e] - bcast((unsigned)hh << 16);
                ah[e] = (short)hh;
                al[e] = (short)rtn16(r1);
            }
        }
        const unsigned short* hp = Bh + (size_t)(kc * NCT) * 512 + l * 8;
        const unsigned short* lp = Bl + (size_t)(kc * NCT) * 512 + l * 8;
#pragma unroll
        for (int ct = 0; ct < NCT; ++ct) {
            bhalf8 bh = *(const bhalf8*)(hp + ct * 512);
            bhalf8 bl = *(const bhalf8*)(lp + ct * 512);
            acc[ct] = __builtin_amdgcn_mfma_f32_16x16x32_bf16(ah, bh, acc[ct], 0, 0, 0);
            acc[ct] = __builtin_amdgcn_mfma_f32_16x16x32_bf16(ah, bl, acc[ct], 0, 0, 0);
            if (!ABF16)
                acc[ct] = __builtin_amdgcn_mfma_f32_16x16x32_bf16(al, bh, acc[ct], 0, 0, 0);
        }
    }
    // D: col = l&15, row = rb + (l>>4)*4 + r   [m89-verified]
    int orow0 = rb + kg * 4;
#pragma unroll
    for (int ct = 0; ct < NCT; ++ct) {
        int j = ct * 16 + (l & 15);
        bool isl = (j < NL);
        int cc = isl ? j : j - NL;
        float bj = isl ? 0.f : bias[cc];
        unsigned short* __restrict__ dp = isl ? zl : zr;
#pragma unroll
        for (int r = 0; r < 4; ++r) {
            int orow = orow0 + r;
            if (orow < nrows) dp[(long)orow * NL + cc] = rtn16(acc[ct][r] + bj);
        }
    }
}

// ---------------- aggregate + combine + epilogue ----------------
// (32 lanes/row x 2 edge-slots): ushort2/lane, chunk=16 edges -> for avg-deg-16
// nodes all 8 row-loads are valid and in flight (2x MLP vs 4-slot), and no
// adds wasted on padding. __shfl always convergent (clamped src, uncond).
// MODE 0/1 write bf16 h rows (OUTT=ushort); MODE 2 writes fp32 (OUTT=float).
template <int NOUT, int MODE, typename OUTT>
__global__ __launch_bounds__(256) void combine_kernel(
    const unsigned short* __restrict__ zl, const unsigned short* __restrict__ zr,
    const int* __restrict__ offs, const int* __restrict__ csr,
    const float* __restrict__ g, const float* __restrict__ bb,
    const float* __restrict__ m, const float* __restrict__ v,
    OUTT* __restrict__ out) {
    int wid  = (blockIdx.x * blockDim.x + threadIdx.x) >> 6;
    int lane = threadIdx.x & 63;
    if (wid >= NNODES) return;          // wave-uniform
    int q   = lane >> 5;            // edge slot 0..1
    int li2 = (lane & 31) * 2;      // column pair
    const bool cok = (li2 < NOUT);
    // hoisted epilogue loads (independent of the gather chain)
    float zr0 = 0.f, zr1 = 0.f;
    float g0 = 0.f, g1 = 0.f, bb0 = 0.f, bb1 = 0.f;
    float m0 = 0.f, m1 = 0.f, v0 = 0.f, v1 = 0.f;
    if (cok) {
        ushort2 zb = *(const ushort2*)&zr[(long)wid * NOUT + li2];
        zr0 = b2f(zb.x); zr1 = b2f(zb.y);
        if (MODE == 1 || MODE == 2) {
            float2 t2;
            t2 = *(const float2*)&g[li2];  g0 = t2.x;  g1 = t2.y;
            t2 = *(const float2*)&bb[li2]; bb0 = t2.x; bb1 = t2.y;
            t2 = *(const float2*)&m[li2];  m0 = t2.x;  m1 = t2.y;
            t2 = *(const float2*)&v[li2];  v0 = t2.x;  v1 = t2.y;
        }
    }
    int s0 = offs[wid], s1 = offs[wid + 1];
    float ax = 0.f, ay = 0.f;
    for (int base = s0; base < s1; base += 64) {   // uniform bounds
        int c = min(64, s1 - base);                // >= 1 here
        int cm1 = c - 1;
        int sv = (base + lane < s1) ? csr[base + lane] : 0;
        for (int p0 = 0; p0 < c; p0 += 16) {       // uniform, 16 edges/chunk
            ushort2 hv[8];
#pragma unroll
            for (int j = 0; j < 8; ++j) {
                int eidx = p0 + 2 * j + q;
                int srow = __shfl(sv, min(eidx, cm1));   // all lanes, convergent
                ushort2 tv = make_ushort2(0, 0);
                if (eidx < c && cok)                     // predicated LOAD only
                    tv = *(const ushort2*)&zl[(long)srow * NOUT + li2];
                hv[j] = tv;
            }
#pragma unroll
            for (int j = 0; j < 8; ++j) {                // unconditional adds
                ax += b2f(hv[j].x); ay += b2f(hv[j].y);
            }
        }
    }
    // reduce across the 2 edge slots — all 64 lanes participate (convergent)
    ax += __shfl_xor(ax, 32);
    ay += __shfl_xor(ay, 32);
    if (q != 0 || !cok) return;
    float invd = 1.f / fmaxf((float)(s1 - s0), 1.f);
    float r0 = ax * invd + zr0;
    float r1 = ay * invd + zr1;
    if (MODE == 1 || MODE == 2) {
        r0 = (r0 - m0) * (g0 * rsqrtf(v0 + 1e-5f)) + bb0;
        r1 = (r1 - m1) * (g1 * rsqrtf(v1 + 1e-5f)) + bb1;
    }
    if (MODE == 0 || MODE == 1) {
        r0 = fmaxf(r0, 0.f); r1 = fmaxf(r1, 0.f);
    }
    if constexpr (MODE == 2) {
        *(float2*)&out[(long)wid * NOUT + li2] = make_float2(r0, r1);
    } else {
        *(ushort2*)&out[(long)wid * NOUT + li2] = make_ushort2(rtn16(r0), rtn16(r1));
    }
}

// ---------------- host ----------------
extern "C" void kernel_launch(void* const* d_in, const int* in_sizes, int n_in,
                              void* d_out, int out_size, void* d_ws, size_t ws_size,
                              hipStream_t stream) {
    const float* x    = (const float*)d_in[0];
    const int*   ei   = (const int*)d_in[1];
    const float* w1l  = (const float*)d_in[2];
    const float* w1r  = (const float*)d_in[3];
    const float* b1   = (const float*)d_in[4];
    const float* wxl  = (const float*)d_in[5];
    const float* wxr  = (const float*)d_in[6];
    const float* bx   = (const float*)d_in[7];
    const float* w2l  = (const float*)d_in[8];
    const float* w2r  = (const float*)d_in[9];
    const float* b2   = (const float*)d_in[10];
    const float* bn3g = (const float*)d_in[11];
    const float* bn3b = (const float*)d_in[12];
    const float* bn3m = (const float*)d_in[13];
    const float* bn3v = (const float*)d_in[14];
    const float* bn2g = (const float*)d_in[15];
    const float* bn2b = (const float*)d_in[16];
    const float* bn2m = (const float*)d_in[17];
    const float* bn2v = (const float*)d_in[18];
    float* out = (float*)d_out;

    char* p = (char*)d_ws;
    auto alloc = [&](size_t bytes) -> void* {
        void* r = (void*)p;
        p += (bytes + 255) & ~(size_t)255;
        return r;
    };
    int*   flag   = (int*)alloc(4);
    int*   bcur   = (int*)alloc(NBK * 4);
    int*   offs   = (int*)alloc((size_t)(NNODES + 1) * 4);
    int*   csr    = (int*)alloc((size_t)NEDGES * 4);
    unsigned short* h16  = (unsigned short*)alloc((size_t)NNODES * 64 * 2); // bf16 h
    unsigned short* zl16 = (unsigned short*)alloc((size_t)NNODES * 64 * 2); // bf16 zl
    unsigned short* zr16 = (unsigned short*)alloc((size_t)NNODES * 64 * 2); // bf16 zr
    unsigned short* B1h = (unsigned short*)alloc(16384 * 2);
    unsigned short* B1l = (unsigned short*)alloc(16384 * 2);
    unsigned short* B2h = (unsigned short*)alloc(8192 * 2);
    unsigned short* B2l = (unsigned short*)alloc(8192 * 2);
    unsigned short* B3h = (unsigned short*)alloc(5120 * 2);
    unsigned short* B3l = (unsigned short*)alloc(5120 * 2);
    // recs (196*9000*4B = 7.1MB) aliases h16 (12.8MB): dead after csr_build,
    // h16 first written by combine layer 1 (stream-ordered after).
    unsigned* recs = (unsigned*)h16;

    hipMemsetAsync(bcur, 0, NBK * 4, stream);
    detect_kernel<<<1, 64, 0, stream>>>(ei, flag);
    bucketize<<<(NEDGES + CHUNK - 1) / CHUNK, 256, 0, stream>>>(ei, flag, recs, bcur);
    prep_w<128, 64, 128><<<64, 256, 0, stream>>>(w1l, w1r, B1h, B1l);
    prep_w<64, 64, 128><<<32, 256, 0, stream>>>(wxl, wxr, B2h, B2l);
    prep_w<64, 40, 80><<<20, 256, 0, stream>>>(w2l, w2r, B3h, B3l);
    csr_build<<<NBK, 512, 0, stream>>>(recs, bcur, offs, csr);

    const int GB = (NNODES + 63) / 64;   // 1563
    // layer 1: x[N,128] (fp32) -> zl/zr -> h1 (bf16, relu)
    gemm_mfma<128, 64, 128, false><<<GB, 256, 0, stream>>>(x, B1h, B1l, b1, zl16, zr16, NNODES);
    combine_kernel<64, 0, unsigned short><<<25000, 256, 0, stream>>>(
        zl16, zr16, offs, csr, nullptr, nullptr, nullptr, nullptr, h16);
    // layer 2: h1 (bf16) -> zl/zr -> h2 (bf16, bn3+relu)
    gemm_mfma<64, 64, 128, true><<<GB, 256, 0, stream>>>(h16, B2h, B2l, bx, zl16, zr16, NNODES);
    combine_kernel<64, 1, unsigned short><<<25000, 256, 0, stream>>>(
        zl16, zr16, offs, csr, bn3g, bn3b, bn3m, bn3v, h16);
    // layer 3: h2 (bf16) -> zl/zr -> out (fp32, bn2)
    gemm_mfma<64, 40, 80, true><<<GB, 256, 0, stream>>>(h16, B3h, B3l, b2, zl16, zr16, NNODES);
    combine_kernel<40, 2, float><<<25000, 256, 0, stream>>>(
        zl16, zr16, offs, csr, bn2g, bn2b, bn2m, bn2v, out);
}

// Round 17
// 226.705 us; speedup vs baseline: 1.6042x; 1.0505x over previous
//
#include <hip/hip_runtime.h>

#define NNODES 100000
#define NEDGES 1600000
#define NBK    196        // buckets of 512 nodes: bk = d >> 9
#define BK_CAP 9000       // mean 8163, sigma ~90 -> +9 sigma
#define CHUNK  4096

typedef short bhalf8 __attribute__((ext_vector_type(8)));   // 8 bf16 bit patterns
typedef float f32x4 __attribute__((ext_vector_type(4)));

__device__ __forceinline__ unsigned fbits(float x){ union{float f;unsigned u;}c; c.f=x; return c.u; }
__device__ __forceinline__ float bcast(unsigned u){ union{float f;unsigned u;}c; c.u=u; return c.f; }
// round-to-nearest-even bf16 (top 16 bits of fp32)
__device__ __forceinline__ unsigned short rtn16(float x){
    unsigned u = fbits(x);
    return (unsigned short)((u + 0x7FFFu + ((u >> 16) & 1u)) >> 16);
}
__device__ __forceinline__ float b2f(unsigned short b){ return bcast((unsigned)b << 16); }

// ---------------- edge dtype detect: int64 vs int32 ----------------
__global__ void detect_kernel(const int* __restrict__ ei, int* __restrict__ flag) {
    int t = threadIdx.x;                 // 0..63
    int v = ei[2 * t + 1];
    unsigned long long nz = __ballot(v != 0);
    if (t == 0) flag[0] = (nz == 0ULL) ? 1 : 0;   // 1 => int64 layout
}

// ---------------- bucketize: ei -> 196 node-range buckets of packed recs ----
__global__ __launch_bounds__(256) void bucketize(
    const int* __restrict__ ei, const int* __restrict__ flag,
    unsigned* __restrict__ recs, int* __restrict__ bcur) {
    const int is64 = flag[0];
    __shared__ int cnt[256], base[256], loc[256], rnk[256];
    __shared__ unsigned stage[CHUNK];
    __shared__ unsigned char bkof[CHUNK];
    const int t = threadIdx.x;
    const long start = (long)blockIdx.x * CHUNK;
    cnt[t] = 0; rnk[t] = 0;
    __syncthreads();
#pragma unroll
    for (int k = 0; k < CHUNK / 256; ++k) {
        long e = start + k * 256 + t;
        if (e < NEDGES) {
            int d = is64 ? ei[2 * (NEDGES + e)] : ei[NEDGES + e];
            atomicAdd(&cnt[d >> 9], 1);
        }
    }
    __syncthreads();
    int v = cnt[t];
    int run = v;
    loc[t] = run;
    __syncthreads();
    for (int off = 1; off < 256; off <<= 1) {
        int other = (t >= off) ? loc[t - off] : 0;
        __syncthreads();
        run += other;
        loc[t] = run;
        __syncthreads();
    }
    int excl = run - v;
    if (v > 0) base[t] = atomicAdd(&bcur[t], v);
    loc[t] = excl;
    __syncthreads();
#pragma unroll
    for (int k = 0; k < CHUNK / 256; ++k) {
        long e = start + k * 256 + t;
        if (e < NEDGES) {
            int s = is64 ? ei[2 * e] : ei[e];
            int d = is64 ? ei[2 * (NEDGES + e)] : ei[NEDGES + e];
            int b = d >> 9;
            int r = atomicAdd(&rnk[b], 1);
            int pos = loc[b] + r;
            stage[pos] = ((unsigned)s << 9) | (unsigned)(d & 511);
            bkof[pos] = (unsigned char)b;
        }
    }
    __syncthreads();
    const int tot = (int)min((long)CHUNK, NEDGES - start);
    for (int i = t; i < tot; i += 256) {
        int b = bkof[i];
        int pos = base[b] + (i - loc[b]);
        if (pos < BK_CAP)
            recs[(size_t)b * BK_CAP + pos] = stage[i];
    }
}

// ---------------- csr_build: one block per bucket, zero global atomics ------
// csr stores BYTE OFFSETS (src*128) into the stride-64-bf16 zl table.
__global__ __launch_bounds__(512) void csr_build(
    const unsigned* __restrict__ recs, const int* __restrict__ bcur,
    int* __restrict__ offs, int* __restrict__ csr) {
    const int b = blockIdx.x;          // 0..195
    const int t = threadIdx.x;         // 0..511
    const int lo = b << 9;
    __shared__ int sc[512];
    __shared__ int hist[512];
    __shared__ int loff[512];
    int bv = (t < NBK) ? bcur[t] : 0;
    int run = bv;
    sc[t] = run;
    __syncthreads();
    for (int off = 1; off < 512; off <<= 1) {
        int other = (t >= off) ? sc[t - off] : 0;
        __syncthreads();
        run += other;
        sc[t] = run;
        __syncthreads();
    }
    const int n = bcur[b];
    const int csr_base = sc[b] - n;    // exclusive
    const unsigned* P = recs + (size_t)b * BK_CAP;
    hist[t] = 0;
    __syncthreads();
    for (int i = t; i < n; i += 512)
        atomicAdd(&hist[P[i] & 511], 1);
    __syncthreads();
    int hv = hist[t];
    int hrun = hv;
    sc[t] = hrun;
    __syncthreads();
    for (int off = 1; off < 512; off <<= 1) {
        int other = (t >= off) ? sc[t - off] : 0;
        __syncthreads();
        hrun += other;
        sc[t] = hrun;
        __syncthreads();
    }
    int ex = hrun - hv;
    loff[t] = ex;
    int node = lo + t;
    if (node < NNODES) offs[node] = csr_base + ex;
    if (b == NBK - 1 && t == 0) offs[NNODES] = NEDGES;
    __syncthreads();
    hist[t] = loff[t];
    __syncthreads();
    for (int i = t; i < n; i += 512) {
        unsigned rec = P[i];
        int r = atomicAdd(&hist[rec & 511], 1);
        csr[csr_base + r] = (int)(rec >> 9) * 128;   // byte offset into zl
    }
}

// ---------------- weight prep: BN-fold + fp32 -> bf16 2-way split (RTN) -----
// w' = w * sc[j], sc = g*rsqrt(v+eps) (or 1 if no BN). bfix = b*sc + bb - m*sc.
template <int K, int NL, int NTOT>
__global__ void prep_w(const float* __restrict__ wl, const float* __restrict__ wr,
                       const float* __restrict__ bias,
                       const float* __restrict__ g, const float* __restrict__ bb,
                       const float* __restrict__ m, const float* __restrict__ vv,
                       unsigned short* __restrict__ Bh, unsigned short* __restrict__ Bl,
                       float* __restrict__ bfix) {
    constexpr int NCT = NTOT / 16;
    constexpr int TOT = (K / 32) * NCT * 512;
    int tid = blockIdx.x * blockDim.x + threadIdx.x;
    if (tid < NL) {
        float sc = g ? g[tid] * rsqrtf(vv[tid] + 1e-5f) : 1.f;
        float sh = g ? (bb[tid] - m[tid] * sc) : 0.f;
        bfix[tid] = bias[tid] * sc + sh;
    }
    for (int idx = tid; idx < TOT; idx += gridDim.x * blockDim.x) {
        int e = idx & 7, l = (idx >> 3) & 63, rest = idx >> 9;
        int ct = rest % NCT, kc = rest / NCT;
        int k = kc * 32 + (l >> 4) * 8 + e;
        int j = ct * 16 + (l & 15);
        int jj = (j < NL) ? j : j - NL;
        float sc = g ? g[jj] * rsqrtf(vv[jj] + 1e-5f) : 1.f;
        float v = ((j < NL) ? wl[k * NL + j] : wr[k * NL + (j - NL)]) * sc;
        unsigned short h = rtn16(v);
        float r1 = v - bcast((unsigned)h << 16);    // exact residual
        Bh[idx] = h;
        Bl[idx] = rtn16(r1);
    }
}

// ---------------- MFMA dual GEMM: Z = h @ [wl|wr] ---------------------------
// ABF16=false: A fp32, 2-way RTN split, 3 MFMA. ABF16=true: A bf16, 2 MFMA.
// zl written bf16 stride 64 (all layers); zr written bf16 stride NL (+bfix).
template <int K, int NL, int NTOT, bool ABF16>
__global__ __launch_bounds__(256) void gemm_mfma(
    const void* __restrict__ hvp, const unsigned short* __restrict__ Bh,
    const unsigned short* __restrict__ Bl, const float* __restrict__ bias,
    unsigned short* __restrict__ zl, unsigned short* __restrict__ zr, int nrows) {
    constexpr int NCT = NTOT / 16;
    constexpr int NKC = K / 32;
    int t = threadIdx.x;
    int l = t & 63, w = t >> 6;
    int rb = blockIdx.x * 64 + w * 16;
    int arow = rb + (l & 15);
    int kg = l >> 4;
    f32x4 acc[NCT];
#pragma unroll
    for (int ct = 0; ct < NCT; ++ct) acc[ct] = (f32x4){0.f, 0.f, 0.f, 0.f};
    const bool aok = (arow < nrows);
#pragma unroll
    for (int kc = 0; kc < NKC; ++kc) {
        bhalf8 ah = {0,0,0,0,0,0,0,0}, al = {0,0,0,0,0,0,0,0};
        if (ABF16) {
            const unsigned short* hr =
                (const unsigned short*)hvp + (long)arow * K + kg * 8;
            if (aok) ah = *(const bhalf8*)(hr + kc * 32);
        } else {
            const float* hr = (const float*)hvp + (long)arow * K + kg * 8;
            float4 a0 = make_float4(0.f, 0.f, 0.f, 0.f), a1 = a0;
            if (aok) {
                a0 = *(const float4*)(hr + kc * 32);
                a1 = *(const float4*)(hr + kc * 32 + 4);
            }
            float av[8] = {a0.x, a0.y, a0.z, a0.w, a1.x, a1.y, a1.z, a1.w};
#pragma unroll
            for (int e = 0; e < 8; ++e) {
                unsigned short hh = rtn16(av[e]);
                float r1 = av[e] - bcast((unsigned)hh << 16);
                ah[e] = (short)hh;
                al[e] = (short)rtn16(r1);
            }
        }
        const unsigned short* hp = Bh + (size_t)(kc * NCT) * 512 + l * 8;
        const unsigned short* lp = Bl + (size_t)(kc * NCT) * 512 + l * 8;
#pragma unroll
        for (int ct = 0; ct < NCT; ++ct) {
            bhalf8 bh = *(const bhalf8*)(hp + ct * 512);
            bhalf8 bl = *(const bhalf8*)(lp + ct * 512);
            acc[ct] = __builtin_amdgcn_mfma_f32_16x16x32_bf16(ah, bh, acc[ct], 0, 0, 0);
            acc[ct] = __builtin_amdgcn_mfma_f32_16x16x32_bf16(ah, bl, acc[ct], 0, 0, 0);
            if (!ABF16)
                acc[ct] = __builtin_amdgcn_mfma_f32_16x16x32_bf16(al, bh, acc[ct], 0, 0, 0);
        }
    }
    // D: col = l&15, row = rb + (l>>4)*4 + r   [m89-verified]
    int orow0 = rb + kg * 4;
#pragma unroll
    for (int ct = 0; ct < NCT; ++ct) {
        int j = ct * 16 + (l & 15);
        bool isl = (j < NL);
        int cc = isl ? j : j - NL;
        float bj = isl ? 0.f : bias[cc];
#pragma unroll
        for (int r = 0; r < 4; ++r) {
            int orow = orow0 + r;
            if (orow < nrows) {
                if (isl) zl[(long)orow * 64 + cc] = rtn16(acc[ct][r]);   // stride 64
                else     zr[(long)orow * NL + cc] = rtn16(acc[ct][r] + bj);
            }
        }
    }
}

// ---------------- aggregate + combine + epilogue (BN pre-folded) ------------
// (32 lanes/row x 2 edge-slots), csr holds BYTE offsets, zl stride 64.
// Full chunks (wave-uniform test) skip all bounds/min. Epilogue: relu(mean+zr).
template <int NOUT, bool RELU, typename OUTT>
__global__ __launch_bounds__(256) void combine_kernel(
    const unsigned short* __restrict__ zl, const unsigned short* __restrict__ zr,
    const int* __restrict__ offs, const int* __restrict__ csr,
    OUTT* __restrict__ out) {
    int wid  = (blockIdx.x * blockDim.x + threadIdx.x) >> 6;
    int lane = threadIdx.x & 63;
    if (wid >= NNODES) return;          // wave-uniform
    int q    = lane >> 5;               // edge slot 0..1
    int li2  = (lane & 31) * 2;         // column pair
    int lib  = li2 * 2;                 // byte offset of column pair
    constexpr bool FULL = (NOUT == 64);
    const bool cok = FULL || (li2 < NOUT);
    const char* zlb = (const char*)zl;
    // hoisted epilogue loads
    float zr0 = 0.f, zr1 = 0.f;
    if (cok) {
        unsigned u = *(const unsigned*)&zr[(long)wid * NOUT + li2];
        zr0 = bcast(u << 16); zr1 = bcast(u & 0xFFFF0000u);
    }
    int s0 = offs[wid], s1 = offs[wid + 1];
    float ax = 0.f, ay = 0.f;
    for (int base = s0; base < s1; base += 64) {   // uniform bounds
        int c = min(64, s1 - base);                // >= 1 here
        int cm1 = c - 1;
        int sv = (base + lane < s1) ? csr[base + lane] : 0;   // byte offsets
        for (int p0 = 0; p0 < c; p0 += 16) {       // uniform, 16 edges/chunk
            unsigned hv[8];
            if (p0 + 16 <= c) {                    // FULL chunk (wave-uniform)
#pragma unroll
                for (int j = 0; j < 8; ++j) {
                    int soff = __shfl(sv, p0 + 2 * j + q);   // convergent
                    unsigned tv = 0;
                    if (cok) tv = *(const unsigned*)(zlb + soff + lib);
                    hv[j] = tv;
                }
            } else {                               // tail chunk (wave-uniform)
#pragma unroll
                for (int j = 0; j < 8; ++j) {
                    int eidx = p0 + 2 * j + q;
                    int soff = __shfl(sv, min(eidx, cm1));   // convergent
                    unsigned tv = 0;
                    if (eidx < c && cok)
                        tv = *(const unsigned*)(zlb + soff + lib);
                    hv[j] = tv;
                }
            }
#pragma unroll
            for (int j = 0; j < 8; ++j) {          // 2-op bf16-pair extract
                ax += bcast(hv[j] << 16);
                ay += bcast(hv[j] & 0xFFFF0000u);
            }
        }
    }
    // reduce across the 2 edge slots — all 64 lanes (convergent)
    ax += __shfl_xor(ax, 32);
    ay += __shfl_xor(ay, 32);
    if (q != 0 || !cok) return;
    float invd = 1.f / fmaxf((float)(s1 - s0), 1.f);
    float r0 = ax * invd + zr0;
    float r1 = ay * invd + zr1;
    if (RELU) { r0 = fmaxf(r0, 0.f); r1 = fmaxf(r1, 0.f); }
    if constexpr (sizeof(OUTT) == 4) {
        *(float2*)&out[(long)wid * NOUT + li2] = make_float2(r0, r1);
    } else {
        *(ushort2*)&out[(long)wid * NOUT + li2] = make_ushort2(rtn16(r0), rtn16(r1));
    }
}

// ---------------- host ----------------
extern "C" void kernel_launch(void* const* d_in, const int* in_sizes, int n_in,
                              void* d_out, int out_size, void* d_ws, size_t ws_size,
                              hipStream_t stream) {
    const float* x    = (const float*)d_in[0];
    const int*   ei   = (const int*)d_in[1];
    const float* w1l  = (const float*)d_in[2];
    const float* w1r  = (const float*)d_in[3];
    const float* b1   = (const float*)d_in[4];
    const float* wxl  = (const float*)d_in[5];
    const float* wxr  = (const float*)d_in[6];
    const float* bx   = (const float*)d_in[7];
    const float* w2l  = (const float*)d_in[8];
    const float* w2r  = (const float*)d_in[9];
    const float* b2   = (const float*)d_in[10];
    const float* bn3g = (const float*)d_in[11];
    const float* bn3b = (const float*)d_in[12];
    const float* bn3m = (const float*)d_in[13];
    const float* bn3v = (const float*)d_in[14];
    const float* bn2g = (const float*)d_in[15];
    const float* bn2b = (const float*)d_in[16];
    const float* bn2m = (const float*)d_in[17];
    const float* bn2v = (const float*)d_in[18];
    float* out = (float*)d_out;

    char* p = (char*)d_ws;
    auto alloc = [&](size_t bytes) -> void* {
        void* r = (void*)p;
        p += (bytes + 255) & ~(size_t)255;
        return r;
    };
    int*   flag   = (int*)alloc(4);
    int*   bcur   = (int*)alloc(NBK * 4);
    int*   offs   = (int*)alloc((size_t)(NNODES + 1) * 4);
    int*   csr    = (int*)alloc((size_t)NEDGES * 4);
    unsigned short* h16  = (unsigned short*)alloc((size_t)NNODES * 64 * 2); // bf16 h
    unsigned short* zl16 = (unsigned short*)alloc((size_t)NNODES * 64 * 2); // bf16 zl (stride 64)
    unsigned short* zr16 = (unsigned short*)alloc((size_t)NNODES * 64 * 2); // bf16 zr
    unsigned short* B1h = (unsigned short*)alloc(16384 * 2);
    unsigned short* B1l = (unsigned short*)alloc(16384 * 2);
    unsigned short* B2h = (unsigned short*)alloc(8192 * 2);
    unsigned short* B2l = (unsigned short*)alloc(8192 * 2);
    unsigned short* B3h = (unsigned short*)alloc(5120 * 2);
    unsigned short* B3l = (unsigned short*)alloc(5120 * 2);
    float* bfix1 = (float*)alloc(64 * 4);
    float* bfix2 = (float*)alloc(64 * 4);
    float* bfix3 = (float*)alloc(40 * 4);
    // recs (7.1MB) aliases h16 (12.8MB): dead after csr_build.
    unsigned* recs = (unsigned*)h16;

    hipMemsetAsync(bcur, 0, NBK * 4, stream);
    detect_kernel<<<1, 64, 0, stream>>>(ei, flag);
    bucketize<<<(NEDGES + CHUNK - 1) / CHUNK, 256, 0, stream>>>(ei, flag, recs, bcur);
    prep_w<128, 64, 128><<<64, 256, 0, stream>>>(w1l, w1r, b1, nullptr, nullptr, nullptr, nullptr, B1h, B1l, bfix1);
    prep_w<64, 64, 128><<<32, 256, 0, stream>>>(wxl, wxr, bx, bn3g, bn3b, bn3m, bn3v, B2h, B2l, bfix2);
    prep_w<64, 40, 80><<<20, 256, 0, stream>>>(w2l, w2r, b2, bn2g, bn2b, bn2m, bn2v, B3h, B3l, bfix3);
    csr_build<<<NBK, 512, 0, stream>>>(recs, bcur, offs, csr);

    const int GB = (NNODES + 63) / 64;   // 1563
    // layer 1: x[N,128] (fp32) -> zl/zr -> h1 (bf16, relu)
    gemm_mfma<128, 64, 128, false><<<GB, 256, 0, stream>>>(x, B1h, B1l, bfix1, zl16, zr16, NNODES);
    combine_kernel<64, true, unsigned short><<<25000, 256, 0, stream>>>(
        zl16, zr16, offs, csr, h16);
    // layer 2: h1 (bf16) -> zl/zr -> h2 (bf16, bn3+relu folded)
    gemm_mfma<64, 64, 128, true><<<GB, 256, 0, stream>>>(h16, B2h, B2l, bfix2, zl16, zr16, NNODES);
    combine_kernel<64, true, unsigned short><<<25000, 256, 0, stream>>>(
        zl16, zr16, offs, csr, h16);
    // layer 3: h2 (bf16) -> zl/zr -> out (fp32, bn2 folded)
    gemm_mfma<64, 40, 80, true><<<GB, 256, 0, stream>>>(h16, B3h, B3l, bfix3, zl16, zr16, NNODES);
    combine_kernel<40, false, float><<<25000, 256, 0, stream>>>(
        zl16, zr16, offs, csr, out);
}

// Round 18
// 220.481 us; speedup vs baseline: 1.6495x; 1.0282x over previous
//
#include <hip/hip_runtime.h>

#define NNODES 100000
#define NEDGES 1600000
#define NBK    196        // buckets of 512 nodes: bk = d >> 9
#define BK_CAP 9000       // raw per-bucket recs cap; mean 8163, sigma ~90
#define BKP    17024      // padded csr per-bucket capacity (9000 + 512*15 + pad)
#define CHUNK  4096
#define ZOFF   (NNODES * 128)   // byte offset of the zero row in zl

typedef short bhalf8 __attribute__((ext_vector_type(8)));   // 8 bf16 bit patterns
typedef float f32x4 __attribute__((ext_vector_type(4)));

__device__ __forceinline__ unsigned fbits(float x){ union{float f;unsigned u;}c; c.f=x; return c.u; }
__device__ __forceinline__ float bcast(unsigned u){ union{float f;unsigned u;}c; c.u=u; return c.f; }
// round-to-nearest-even bf16 (top 16 bits of fp32)
__device__ __forceinline__ unsigned short rtn16(float x){
    unsigned u = fbits(x);
    return (unsigned short)((u + 0x7FFFu + ((u >> 16) & 1u)) >> 16);
}

// ---------------- bucketize: ei -> 196 node-range buckets of packed recs ----
// Per-block inline int64/int32 detect; int2 (8B) coalesced edge reads.
// rec = (src << 9) | (dst & 511).
__global__ __launch_bounds__(256) void bucketize(
    const int* __restrict__ ei, unsigned* __restrict__ recs, int* __restrict__ bcur) {
    __shared__ int s_is64;
    __shared__ int cnt[256], base[256], loc[256], rnk[256];
    __shared__ unsigned stage[CHUNK];
    __shared__ unsigned char bkof[CHUNK];
    const int t = threadIdx.x;
    if (t < 64) {   // wave-0 detect: int64 => odd 32-bit words all zero
        int v = ei[2 * t + 1];
        unsigned long long nz = __ballot(v != 0);
        if (t == 0) s_is64 = (nz == 0ULL) ? 1 : 0;
    }
    cnt[t] = 0; rnk[t] = 0;
    __syncthreads();
    const int is64 = s_is64;
    const long start = (long)blockIdx.x * CHUNK;
    const int2* ei2 = (const int2*)ei;
#pragma unroll
    for (int k = 0; k < CHUNK / 256; ++k) {
        long e = start + k * 256 + t;
        if (e < NEDGES) {
            int d = is64 ? ei2[NEDGES + e].x : ei[NEDGES + e];
            atomicAdd(&cnt[d >> 9], 1);
        }
    }
    __syncthreads();
    int v = cnt[t];
    int run = v;
    loc[t] = run;
    __syncthreads();
    for (int off = 1; off < 256; off <<= 1) {
        int other = (t >= off) ? loc[t - off] : 0;
        __syncthreads();
        run += other;
        loc[t] = run;
        __syncthreads();
    }
    int excl = run - v;
    if (v > 0) base[t] = atomicAdd(&bcur[t], v);
    loc[t] = excl;
    __syncthreads();
#pragma unroll
    for (int k = 0; k < CHUNK / 256; ++k) {
        long e = start + k * 256 + t;
        if (e < NEDGES) {
            int s = is64 ? ei2[e].x : ei[e];
            int d = is64 ? ei2[NEDGES + e].x : ei[NEDGES + e];
            int b = d >> 9;
            int r = atomicAdd(&rnk[b], 1);
            int pos = loc[b] + r;
            stage[pos] = ((unsigned)s << 9) | (unsigned)(d & 511);
            bkof[pos] = (unsigned char)b;
        }
    }
    __syncthreads();
    const int tot = (int)min((long)CHUNK, NEDGES - start);
    for (int i = t; i < tot; i += 256) {
        int b = bkof[i];
        int pos = base[b] + (i - loc[b]);
        if (pos < BK_CAP)
            recs[(size_t)b * BK_CAP + pos] = stage[i];
    }
}

// ---------------- csr_build: padded lists, fixed bucket capacity ------------
// Per node: padded size = ceil(deg/16)*16; padding entries point to the zero
// row (ZOFF). offs2 = (start, padded_end); degs = real degree. csr = src*128.
__global__ __launch_bounds__(512) void csr_build(
    const unsigned* __restrict__ recs, const int* __restrict__ bcur,
    int2* __restrict__ offs2, int* __restrict__ degs, int* __restrict__ csr) {
    const int b = blockIdx.x;          // 0..195
    const int t = threadIdx.x;         // 0..511
    const int lo = b << 9;
    __shared__ int sc[512];
    __shared__ int hist[512];
    __shared__ int lstart[512];
    const int n = bcur[b];
    const unsigned* P = recs + (size_t)b * BK_CAP;
    hist[t] = 0;
    __syncthreads();
    for (int i = t; i < n; i += 512)
        atomicAdd(&hist[P[i] & 511], 1);
    __syncthreads();
    const int deg = hist[t];
    const int pad = (deg + 15) & ~15;
    int run = pad;
    sc[t] = run;
    __syncthreads();
    for (int off = 1; off < 512; off <<= 1) {
        int other = (t >= off) ? sc[t - off] : 0;
        __syncthreads();
        run += other;
        sc[t] = run;
        __syncthreads();
    }
    const int start = b * BKP + (run - pad);
    lstart[t] = start;
    const int node = lo + t;
    if (node < NNODES) {
        offs2[node] = make_int2(start, start + pad);
        degs[node] = deg;
    }
    hist[t] = 0;                       // reuse as cursor
    __syncthreads();
    for (int i = t; i < n; i += 512) {
        unsigned rec = P[i];
        int d = rec & 511;
        int r = atomicAdd(&hist[d], 1);
        csr[lstart[d] + r] = (int)(rec >> 9) * 128;   // byte offset into zl
    }
    __syncthreads();
    for (int i = deg; i < pad; ++i)    // padding -> zero row
        csr[start + i] = ZOFF;
}

// ---------------- weight prep (fused 3 layers): BN-fold + bf16 2-way split --
template <int K, int NL, int NTOT>
__device__ __forceinline__ void prep_section(
    int blk, int nblk, const float* wl, const float* wr, const float* bias,
    const float* g, const float* bb, const float* m, const float* vv,
    unsigned short* Bh, unsigned short* Bl, float* bfix) {
    constexpr int NCT = NTOT / 16;
    constexpr int TOT = (K / 32) * NCT * 512;
    int tid = blk * 256 + threadIdx.x;
    if (tid < NL) {
        float sc = g ? g[tid] * rsqrtf(vv[tid] + 1e-5f) : 1.f;
        float sh = g ? (bb[tid] - m[tid] * sc) : 0.f;
        bfix[tid] = bias[tid] * sc + sh;
    }
    for (int idx = tid; idx < TOT; idx += nblk * 256) {
        int e = idx & 7, l = (idx >> 3) & 63, rest = idx >> 9;
        int ct = rest % NCT, kc = rest / NCT;
        int k = kc * 32 + (l >> 4) * 8 + e;
        int j = ct * 16 + (l & 15);
        int jj = (j < NL) ? j : j - NL;
        float sc = g ? g[jj] * rsqrtf(vv[jj] + 1e-5f) : 1.f;
        float v = ((j < NL) ? wl[k * NL + j] : wr[k * NL + (j - NL)]) * sc;
        unsigned short h = rtn16(v);
        float r1 = v - bcast((unsigned)h << 16);
        Bh[idx] = h;
        Bl[idx] = rtn16(r1);
    }
}

__global__ __launch_bounds__(256) void prep_all(
    const float* w1l, const float* w1r, const float* b1,
    const float* wxl, const float* wxr, const float* bx,
    const float* w2l, const float* w2r, const float* b2,
    const float* g3, const float* bb3, const float* m3, const float* v3,
    const float* g2, const float* bb2, const float* m2, const float* v2,
    unsigned short* B1h, unsigned short* B1l, float* bf1,
    unsigned short* B2h, unsigned short* B2l, float* bf2,
    unsigned short* B3h, unsigned short* B3l, float* bf3) {
    int blk = blockIdx.x;
    if (blk < 64)
        prep_section<128, 64, 128>(blk, 64, w1l, w1r, b1,
                                   nullptr, nullptr, nullptr, nullptr, B1h, B1l, bf1);
    else if (blk < 96)
        prep_section<64, 64, 128>(blk - 64, 32, wxl, wxr, bx,
                                  g3, bb3, m3, v3, B2h, B2l, bf2);
    else
        prep_section<64, 40, 80>(blk - 96, 20, w2l, w2r, b2,
                                 g2, bb2, m2, v2, B3h, B3l, bf3);
}

// ---------------- MFMA dual GEMM: Z = h @ [wl|wr] ---------------------------
// ABF16=false: A fp32, 2-way RTN split, 3 MFMA. ABF16=true: A bf16, 2 MFMA.
// zl written bf16 STRIDE 64 (all layers) + ZERO ROW at orow==nrows;
// zr written bf16 stride NL (+bfix).
template <int K, int NL, int NTOT, bool ABF16>
__global__ __launch_bounds__(256) void gemm_mfma(
    const void* __restrict__ hvp, const unsigned short* __restrict__ Bh,
    const unsigned short* __restrict__ Bl, const float* __restrict__ bias,
    unsigned short* __restrict__ zl, unsigned short* __restrict__ zr, int nrows) {
    constexpr int NCT = NTOT / 16;
    constexpr int NKC = K / 32;
    int t = threadIdx.x;
    int l = t & 63, w = t >> 6;
    int rb = blockIdx.x * 64 + w * 16;
    int arow = rb + (l & 15);
    int kg = l >> 4;
    f32x4 acc[NCT];
#pragma unroll
    for (int ct = 0; ct < NCT; ++ct) acc[ct] = (f32x4){0.f, 0.f, 0.f, 0.f};
    const bool aok = (arow < nrows);
#pragma unroll
    for (int kc = 0; kc < NKC; ++kc) {
        bhalf8 ah = {0,0,0,0,0,0,0,0}, al = {0,0,0,0,0,0,0,0};
        if (ABF16) {
            const unsigned short* hr =
                (const unsigned short*)hvp + (long)arow * K + kg * 8;
            if (aok) ah = *(const bhalf8*)(hr + kc * 32);
        } else {
            const float* hr = (const float*)hvp + (long)arow * K + kg * 8;
            float4 a0 = make_float4(0.f, 0.f, 0.f, 0.f), a1 = a0;
            if (aok) {
                a0 = *(const float4*)(hr + kc * 32);
                a1 = *(const float4*)(hr + kc * 32 + 4);
            }
            float av[8] = {a0.x, a0.y, a0.z, a0.w, a1.x, a1.y, a1.z, a1.w};
#pragma unroll
            for (int e = 0; e < 8; ++e) {
                unsigned short hh = rtn16(av[e]);
                float r1 = av[e] - bcast((unsigned)hh << 16);
                ah[e] = (short)hh;
                al[e] = (short)rtn16(r1);
            }
        }
        const unsigned short* hp = Bh + (size_t)(kc * NCT) * 512 + l * 8;
        const unsigned short* lp = Bl + (size_t)(kc * NCT) * 512 + l * 8;
#pragma unroll
        for (int ct = 0; ct < NCT; ++ct) {
            bhalf8 bh = *(const bhalf8*)(hp + ct * 512);
            bhalf8 bl = *(const bhalf8*)(lp + ct * 512);
            acc[ct] = __builtin_amdgcn_mfma_f32_16x16x32_bf16(ah, bh, acc[ct], 0, 0, 0);
            acc[ct] = __builtin_amdgcn_mfma_f32_16x16x32_bf16(ah, bl, acc[ct], 0, 0, 0);
            if (!ABF16)
                acc[ct] = __builtin_amdgcn_mfma_f32_16x16x32_bf16(al, bh, acc[ct], 0, 0, 0);
        }
    }
    // D: col = l&15, row = rb + (l>>4)*4 + r   [m89-verified]
    int orow0 = rb + kg * 4;
#pragma unroll
    for (int ct = 0; ct < NCT; ++ct) {
        int j = ct * 16 + (l & 15);
        bool isl = (j < NL);
        int cc = isl ? j : j - NL;
        float bj = isl ? 0.f : bias[cc];
#pragma unroll
        for (int r = 0; r < 4; ++r) {
            int orow = orow0 + r;
            if (orow < nrows) {
                if (isl) zl[(long)orow * 64 + cc] = rtn16(acc[ct][r]);   // stride 64
                else     zr[(long)orow * NL + cc] = rtn16(acc[ct][r] + bj);
            } else if (orow == nrows && isl) {
                zl[(long)orow * 64 + cc] = 0;                            // zero row
            }
        }
    }
}

// ---------------- aggregate + combine + epilogue (BN pre-folded) ------------
// Padded lists => every chunk is full: 8 shfl + 8 loads + 16 pair-adds, zero
// conditionals. Loads unguarded (padding -> zero row; dead lanes in-bounds).
// __shfl unconditional & convergent throughout.
template <int NOUT, bool RELU, typename OUTT>
__global__ __launch_bounds__(256) void combine_kernel(
    const unsigned short* __restrict__ zl, const unsigned short* __restrict__ zr,
    const int2* __restrict__ offs2, const int* __restrict__ degs,
    const int* __restrict__ csr, OUTT* __restrict__ out) {
    int wid  = (blockIdx.x * blockDim.x + threadIdx.x) >> 6;
    int lane = threadIdx.x & 63;
    if (wid >= NNODES) return;          // wave-uniform
    int q    = lane >> 5;               // edge slot 0..1
    int li2  = (lane & 31) * 2;         // column pair
    unsigned lib = (unsigned)li2 * 2;   // byte offset of column pair
    const char* zlb = (const char*)zl;
    // hoisted epilogue loads (unguarded; dead lanes discard)
    unsigned uzr = *(const unsigned*)&zr[(long)wid * NOUT + li2];
    float zr0 = bcast(uzr << 16), zr1 = bcast(uzr & 0xFFFF0000u);
    float invd = 1.f / fmaxf((float)degs[wid], 1.f);
    int2 se = offs2[wid];
    float ax = 0.f, ay = 0.f;
    for (int base = se.x; base < se.y; base += 64) {   // uniform bounds
        int c = min(64, se.y - base);                  // multiple of 16
        int sv = csr[base + lane];                     // byte offsets (padded)
        for (int p0 = 0; p0 < c; p0 += 16) {           // uniform, full chunks
            unsigned hv[8];
#pragma unroll
            for (int j = 0; j < 8; ++j) {
                unsigned soff = (unsigned)__shfl(sv, p0 + 2 * j + q);  // convergent
                hv[j] = *(const unsigned*)(zlb + soff + lib);
            }
#pragma unroll
            for (int j = 0; j < 8; ++j) {              // 2-op bf16-pair extract
                ax += bcast(hv[j] << 16);
                ay += bcast(hv[j] & 0xFFFF0000u);
            }
        }
    }
    // reduce across the 2 edge slots — all 64 lanes (convergent)
    ax += __shfl_xor(ax, 32);
    ay += __shfl_xor(ay, 32);
    if (q != 0 || li2 >= NOUT) return;
    float r0 = ax * invd + zr0;
    float r1 = ay * invd + zr1;
    if (RELU) { r0 = fmaxf(r0, 0.f); r1 = fmaxf(r1, 0.f); }
    if constexpr (sizeof(OUTT) == 4) {
        *(float2*)&out[(long)wid * NOUT + li2] = make_float2(r0, r1);
    } else {
        *(ushort2*)&out[(long)wid * NOUT + li2] = make_ushort2(rtn16(r0), rtn16(r1));
    }
}

// ---------------- host ----------------
extern "C" void kernel_launch(void* const* d_in, const int* in_sizes, int n_in,
                              void* d_out, int out_size, void* d_ws, size_t ws_size,
                              hipStream_t stream) {
    const float* x    = (const float*)d_in[0];
    const int*   ei   = (const int*)d_in[1];
    const float* w1l  = (const float*)d_in[2];
    const float* w1r  = (const float*)d_in[3];
    const float* b1   = (const float*)d_in[4];
    const float* wxl  = (const float*)d_in[5];
    const float* wxr  = (const float*)d_in[6];
    const float* bx   = (const float*)d_in[7];
    const float* w2l  = (const float*)d_in[8];
    const float* w2r  = (const float*)d_in[9];
    const float* b2   = (const float*)d_in[10];
    const float* bn3g = (const float*)d_in[11];
    const float* bn3b = (const float*)d_in[12];
    const float* bn3m = (const float*)d_in[13];
    const float* bn3v = (const float*)d_in[14];
    const float* bn2g = (const float*)d_in[15];
    const float* bn2b = (const float*)d_in[16];
    const float* bn2m = (const float*)d_in[17];
    const float* bn2v = (const float*)d_in[18];
    float* out = (float*)d_out;

    char* p = (char*)d_ws;
    auto alloc = [&](size_t bytes) -> void* {
        void* r = (void*)p;
        p += (bytes + 255) & ~(size_t)255;
        return r;
    };
    int*   bcur  = (int*)alloc(NBK * 4);
    int2*  offs2 = (int2*)alloc((size_t)NNODES * 8);
    int*   degs  = (int*)alloc((size_t)NNODES * 4);
    int*   csr   = (int*)alloc(((size_t)NBK * BKP + 64) * 4);
    unsigned short* h16  = (unsigned short*)alloc((size_t)NNODES * 64 * 2);       // bf16 h
    unsigned short* zl16 = (unsigned short*)alloc((size_t)(NNODES + 1) * 64 * 2); // bf16 zl + zero row
    unsigned short* zr16 = (unsigned short*)alloc((size_t)NNODES * 64 * 2);       // bf16 zr
    unsigned short* B1h = (unsigned short*)alloc(16384 * 2);
    unsigned short* B1l = (unsigned short*)alloc(16384 * 2);
    unsigned short* B2h = (unsigned short*)alloc(8192 * 2);
    unsigned short* B2l = (unsigned short*)alloc(8192 * 2);
    unsigned short* B3h = (unsigned short*)alloc(5120 * 2);
    unsigned short* B3l = (unsigned short*)alloc(5120 * 2);
    float* bfix1 = (float*)alloc(64 * 4);
    float* bfix2 = (float*)alloc(64 * 4);
    float* bfix3 = (float*)alloc(40 * 4);
    // recs (7.1MB) aliases h16 (12.8MB): dead after csr_build; h16 first
    // written by combine layer 1 (stream-ordered after).
    unsigned* recs = (unsigned*)h16;

    hipMemsetAsync(bcur, 0, NBK * 4, stream);
    bucketize<<<(NEDGES + CHUNK - 1) / CHUNK, 256, 0, stream>>>(ei, recs, bcur);
    prep_all<<<116, 256, 0, stream>>>(w1l, w1r, b1, wxl, wxr, bx, w2l, w2r, b2,
                                      bn3g, bn3b, bn3m, bn3v, bn2g, bn2b, bn2m, bn2v,
                                      B1h, B1l, bfix1, B2h, B2l, bfix2, B3h, B3l, bfix3);
    csr_build<<<NBK, 512, 0, stream>>>(recs, bcur, offs2, degs, csr);

    const int GB = (NNODES + 63) / 64;   // 1563 (covers row NNODES for zero row)
    // layer 1: x[N,128] (fp32) -> zl/zr -> h1 (bf16, relu)
    gemm_mfma<128, 64, 128, false><<<GB, 256, 0, stream>>>(x, B1h, B1l, bfix1, zl16, zr16, NNODES);
    combine_kernel<64, true, unsigned short><<<25000, 256, 0, stream>>>(
        zl16, zr16, offs2, degs, csr, h16);
    // layer 2: h1 (bf16) -> zl/zr -> h2 (bf16, bn3+relu folded)
    gemm_mfma<64, 64, 128, true><<<GB, 256, 0, stream>>>(h16, B2h, B2l, bfix2, zl16, zr16, NNODES);
    combine_kernel<64, true, unsigned short><<<25000, 256, 0, stream>>>(
        zl16, zr16, offs2, degs, csr, h16);
    // layer 3: h2 (bf16) -> zl/zr -> out (fp32, bn2 folded)
    gemm_mfma<64, 40, 80, true><<<GB, 256, 0, stream>>>(h16, B3h, B3l, bfix3, zl16, zr16, NNODES);
    combine_kernel<40, false, float><<<25000, 256, 0, stream>>>(
        zl16, zr16, offs2, degs, csr, out);
}